// Round 5
// baseline (466.472 us; speedup 1.0000x reference)
//
#include <hip/hip_runtime.h>
#include <stdint.h>
#include <math.h>

// DeeperGNN forward on MI355X.
// R5: B-resident-in-LDS GEMM (k_gemmL), barrier-free K-loop, A direct global->VGPR.
// encoders -> per layer { msg aggregation -> GEMM1 -> LN512 -> GEMM2(+res) -> preLN }
// -> head. f32 residual/LN stats; bf16 GEMM operands + edge encodings.

typedef __bf16 bf16x8 __attribute__((ext_vector_type(8)));
typedef __bf16 bf16x4 __attribute__((ext_vector_type(4)));
typedef float  f32x4  __attribute__((ext_vector_type(4)));

constexpr int NN   = 16384;   // nodes
constexpr int NE   = 131072;  // edges
constexpr int DIN  = 128;
constexpr int DE   = 64;
constexpr int HD   = 256;
constexpr int HD2  = 512;

__device__ __forceinline__ void gl_lds16(const __bf16* g, __bf16* l) {
  __builtin_amdgcn_global_load_lds((const __attribute__((address_space(1))) void*)g,
                                   (__attribute__((address_space(3))) void*)l, 16, 0, 0);
}

// ---------------- CSR build ----------------
__global__ void k_hist(const int* __restrict__ dst, int* __restrict__ deg) {
  int e = blockIdx.x * 256 + threadIdx.x;
  if (e < NE) atomicAdd(&deg[dst[e]], 1);
}

__global__ __launch_bounds__(1024) void k_scan(const int* __restrict__ deg,
                                               int* __restrict__ row_start) {
  __shared__ int part[1024];
  const int t = threadIdx.x;
  const int base = t * 16;
  int loc[16];
  int s = 0;
  #pragma unroll
  for (int i = 0; i < 16; i++) { loc[i] = s; s += deg[base + i]; }
  part[t] = s;
  __syncthreads();
  for (int off = 1; off < 1024; off <<= 1) {
    int v = (t >= off) ? part[t - off] : 0;
    __syncthreads();
    part[t] += v;
    __syncthreads();
  }
  const int excl = (t == 0) ? 0 : part[t - 1];
  #pragma unroll
  for (int i = 0; i < 16; i++) row_start[base + i] = excl + loc[i];
}

__global__ void k_scatter(const int* __restrict__ src, const int* __restrict__ dst,
                          const int* __restrict__ row_start, int* __restrict__ cursor,
                          int2* __restrict__ csr_es) {
  int e = blockIdx.x * 256 + threadIdx.x;
  if (e >= NE) return;
  const int d = dst[e];
  const int p = atomicAdd(&cursor[d], 1);
  csr_es[row_start[d] + p] = make_int2(e, src[e]);
}

// canonical per-node eid-order (determinism); one thread per node, deg ~8
__global__ void k_sort(const int* __restrict__ row_start, const int* __restrict__ deg,
                       int2* __restrict__ csr_es) {
  int n = blockIdx.x * 256 + threadIdx.x;
  if (n >= NN) return;
  const int st = row_start[n], dg = deg[n];
  for (int a = 1; a < dg; a++) {
    int2 k = csr_es[st + a];
    int b = a - 1;
    while (b >= 0 && csr_es[st + b].x > k.x) { csr_es[st + b + 1] = csr_es[st + b]; b--; }
    csr_es[st + b + 1] = k;
  }
}

// ---------------- merged prep: weight transposes + input bf16 casts ----------------
__global__ void k_prep(const float* __restrict__ enc_w, const float* __restrict__ ee_w,
                       const float* __restrict__ w1, const float* __restrict__ w2,
                       const float* __restrict__ x, const float* __restrict__ ea,
                       __bf16* __restrict__ enc_wT, __bf16* __restrict__ ee_wT,
                       __bf16* __restrict__ w1T, __bf16* __restrict__ w2T,
                       __bf16* __restrict__ xbf, __bf16* __restrict__ eabf) {
  int i = blockIdx.x * 256 + threadIdx.x;
  const int S0 = DIN * HD, S1 = DE * HD, S2 = 4 * HD * HD2, S3 = 4 * HD2 * HD;
  const int S4 = NN * DIN / 4, S5 = NE * DE / 4;
  if (i < S0) { int k = i / HD, n = i % HD; enc_wT[n * DIN + k] = (__bf16)enc_w[i]; return; }
  i -= S0;
  if (i < S1) { int k = i / HD, n = i % HD; ee_wT[n * DE + k] = (__bf16)ee_w[i]; return; }
  i -= S1;
  if (i < S2) {
    int l = i / (HD * HD2), r = i % (HD * HD2), k = r / HD2, n = r % HD2;
    w1T[(size_t)l * HD * HD2 + (size_t)n * HD + k] = (__bf16)w1[i]; return;
  }
  i -= S2;
  if (i < S3) {
    int l = i / (HD2 * HD), r = i % (HD2 * HD), k = r / HD, n = r % HD;
    w2T[(size_t)l * HD2 * HD + (size_t)n * HD2 + k] = (__bf16)w2[i]; return;
  }
  i -= S3;
  if (i < S4) {
    float4 v = ((const float4*)x)[i];
    bf16x4 r; r[0] = (__bf16)v.x; r[1] = (__bf16)v.y; r[2] = (__bf16)v.z; r[3] = (__bf16)v.w;
    ((bf16x4*)xbf)[i] = r; return;
  }
  i -= S4;
  if (i < S5) {
    float4 v = ((const float4*)ea)[i];
    bf16x4 r; r[0] = (__bf16)v.x; r[1] = (__bf16)v.y; r[2] = (__bf16)v.z; r[3] = (__bf16)v.w;
    ((bf16x4*)eabf)[i] = r; return;
  }
}

// ---------------- B-resident GEMM: C[M,Nn] = A[M,KLEN] * BT[Nn,KLEN] + bias (+R) ----
// Tile 128 rows x 64 cols, 4 waves in 2x2 (each 64x32). B-tile [KLEN/8][64][8] fully
// preloaded to LDS (one barrier); K-loop barrier-free: A read global->VGPR, B from LDS.
// OUT: 0=f32 C, 1=bf16 Cb, 2=dual (f32 C + bf16 Cb).
template <int KLEN, int RES, int OUT>
__global__ __launch_bounds__(256, (KLEN == 512) ? 2 : 3)
void k_gemmL(const __bf16* __restrict__ A, const __bf16* __restrict__ BT,
             const float* __restrict__ bias, const float* __restrict__ R,
             float* __restrict__ Cf, __bf16* __restrict__ Cb, int Nn) {
  __shared__ __bf16 lsB[64 * KLEN];
  const int tid = threadIdx.x, lane = tid & 63, wv = tid >> 6;
  const int ncg = Nn >> 6;
  const int bn = (int)blockIdx.x % ncg;        // fast: col-groups share A rows in L2
  const size_t row0 = (size_t)((int)blockIdx.x / ncg) * 128;
  const int col0 = bn * 64;
  const int wr = (wv >> 1) * 64, wc = (wv & 1) * 32;
  const int fr = lane & 15, ks = lane >> 4;

  // preload B-tile (one-time): chunk c -> col=c&63, kblk=c>>6 ; LDS [kblk][col][8]
  #pragma unroll
  for (int j = 0; j < KLEN / 32; j++) {
    const int c = j * 256 + tid;
    gl_lds16(BT + (size_t)(col0 + (c & 63)) * KLEN + (c >> 6) * 8, &lsB[c * 8]);
  }
  __syncthreads();

  f32x4 acc[4][2] = {};
  #pragma unroll 2
  for (int k0 = 0; k0 < KLEN; k0 += 32) {
    bf16x8 af[4], bf[2];
    #pragma unroll
    for (int m = 0; m < 4; m++)
      af[m] = *(const bf16x8*)&A[(row0 + wr + m * 16 + fr) * KLEN + k0 + ks * 8];
    #pragma unroll
    for (int n = 0; n < 2; n++)
      bf[n] = *(const bf16x8*)&lsB[((((k0 >> 3) + ks) << 6) + wc + n * 16 + fr) * 8];
    #pragma unroll
    for (int m = 0; m < 4; m++)
      #pragma unroll
      for (int n = 0; n < 2; n++)
        acc[m][n] = __builtin_amdgcn_mfma_f32_16x16x32_bf16(af[m], bf[n], acc[m][n], 0, 0, 0);
  }

  const int fq = ks;
  #pragma unroll
  for (int m = 0; m < 4; m++) {
    #pragma unroll
    for (int n = 0; n < 2; n++) {
      const size_t gcol = col0 + wc + n * 16 + fr;
      const float bv = bias[gcol];
      #pragma unroll
      for (int r = 0; r < 4; r++) {
        const size_t grow = row0 + wr + m * 16 + fq * 4 + r;
        float v = acc[m][n][r] + bv;
        if (RES) v += R[grow * Nn + gcol];
        if (OUT == 0 || OUT == 2) Cf[grow * Nn + gcol] = v;
        if (OUT == 1 || OUT == 2) Cb[grow * Nn + gcol] = (__bf16)v;
      }
    }
  }
}

// ---------------- wave-per-node softmax aggregation ----------------
// 4-edge load groups: 8 gathers in flight before consumption (latency hiding).
__global__ __launch_bounds__(256)
void k_msg(const __bf16* __restrict__ zb, const __bf16* __restrict__ ebf,
           const int* __restrict__ row_start, const int* __restrict__ deg,
           const int2* __restrict__ csr_es, const float* __restrict__ tvec,
           int layer, __bf16* __restrict__ a1) {
  const int wv   = __builtin_amdgcn_readfirstlane(threadIdx.x >> 6);
  const int lane = threadIdx.x & 63;
  const int node = blockIdx.x * 4 + wv;
  const int st = __builtin_amdgcn_readfirstlane(row_start[node]);
  const int dg = __builtin_amdgcn_readfirstlane(deg[node]);
  const float t = tvec[layer];
  const int f0 = lane * 4;

  int my_eid = 0, my_src = 0;
  if (lane < dg) { int2 pr = csr_es[st + lane]; my_eid = pr.x; my_src = pr.y; }

  float den[4] = {0.f, 0.f, 0.f, 0.f}, agg[4] = {0.f, 0.f, 0.f, 0.f};
  const int dmain = dg < 64 ? dg : 64;
  int j = 0;
  for (; j + 4 <= dmain; j += 4) {
    bf16x4 zv[4], ev[4];
    #pragma unroll
    for (int u = 0; u < 4; u++) {
      const int eid = __builtin_amdgcn_readlane(my_eid, j + u);
      const int sn  = __builtin_amdgcn_readlane(my_src, j + u);
      zv[u] = *(const bf16x4*)&zb[(size_t)sn * HD + f0];
      ev[u] = *(const bf16x4*)&ebf[(size_t)eid * HD + f0];
    }
    #pragma unroll
    for (int u = 0; u < 4; u++)
      #pragma unroll
      for (int q = 0; q < 4; q++) {
        const float m  = fmaxf((float)zv[u][q] + (float)ev[u][q], 0.f) + 1e-7f;
        const float ex = __expf(m * t);
        den[q] += ex;
        agg[q] += m * ex;
      }
  }
  for (; j < dmain; j++) {
    const int eid = __builtin_amdgcn_readlane(my_eid, j);
    const int sn  = __builtin_amdgcn_readlane(my_src, j);
    const bf16x4 zv = *(const bf16x4*)&zb[(size_t)sn * HD + f0];
    const bf16x4 ev = *(const bf16x4*)&ebf[(size_t)eid * HD + f0];
    #pragma unroll
    for (int q = 0; q < 4; q++) {
      const float m  = fmaxf((float)zv[q] + (float)ev[q], 0.f) + 1e-7f;
      const float ex = __expf(m * t);
      den[q] += ex;
      agg[q] += m * ex;
    }
  }
  for (int jj = 64; jj < dg; jj++) {  // cold path
    const int2 pr = csr_es[st + jj];
    const bf16x4 zv = *(const bf16x4*)&zb[(size_t)pr.y * HD + f0];
    const bf16x4 ev = *(const bf16x4*)&ebf[(size_t)pr.x * HD + f0];
    #pragma unroll
    for (int q = 0; q < 4; q++) {
      const float m  = fmaxf((float)zv[q] + (float)ev[q], 0.f) + 1e-7f;
      const float ex = __expf(m * t);
      den[q] += ex;
      agg[q] += m * ex;
    }
  }
  const bf16x4 sv = *(const bf16x4*)&zb[(size_t)node * HD + f0];
  bf16x4 r;
  #pragma unroll
  for (int q = 0; q < 4; q++) {
    const float res = (dg > 0) ? agg[q] / (den[q] + 1e-16f) : 0.f;
    r[q] = (__bf16)(res + (float)sv[q]);
  }
  *(bf16x4*)&a1[(size_t)node * HD + f0] = r;
}

// ---------------- LN kernels ----------------
// zb = bf16(relu(LN_256(h))). 4 rows/block, 64 lanes x 4 feats.
__global__ __launch_bounds__(256)
void k_prenorm(const float* __restrict__ h, const float* __restrict__ g,
               const float* __restrict__ b, __bf16* __restrict__ zb) {
  const int row  = blockIdx.x * 4 + (threadIdx.x >> 6);
  const int lane = threadIdx.x & 63;
  const float4 v = *(const float4*)&h[(size_t)row * HD + lane * 4];
  float s = v.x + v.y + v.z + v.w;
  for (int o = 1; o < 64; o <<= 1) s += __shfl_xor(s, o);
  const float mu = s * (1.f / HD);
  const float dx = v.x - mu, dy = v.y - mu, dz = v.z - mu, dw = v.w - mu;
  float q = dx * dx + dy * dy + dz * dz + dw * dw;
  for (int o = 1; o < 64; o <<= 1) q += __shfl_xor(q, o);
  const float inv = rsqrtf(q * (1.f / HD) + 1e-5f);
  const float4 gv = *(const float4*)&g[lane * 4];
  const float4 bv = *(const float4*)&b[lane * 4];
  bf16x4 r;
  r[0] = (__bf16)fmaxf(dx * inv * gv.x + bv.x, 0.f);
  r[1] = (__bf16)fmaxf(dy * inv * gv.y + bv.y, 0.f);
  r[2] = (__bf16)fmaxf(dz * inv * gv.z + bv.z, 0.f);
  r[3] = (__bf16)fmaxf(dw * inv * gv.w + bv.w, 0.f);
  *(bf16x4*)&zb[(size_t)row * HD + lane * 4] = r;
}

// a2 = bf16(relu(LN_512(c1b))), 2 rows/block, 2 waves/row, bf16x4/lane.
__global__ __launch_bounds__(256)
void k_ln512(const __bf16* __restrict__ c1b, const float* __restrict__ g,
             const float* __restrict__ b, __bf16* __restrict__ a2) {
  __shared__ float sred[2][2][2];
  const int tid = threadIdx.x, lane = tid & 63, wv = tid >> 6;
  const int rib = wv >> 1, half = wv & 1;
  const int row = blockIdx.x * 2 + rib;
  const int idx = (half * 64 + lane) * 4;
  const bf16x4 v = *(const bf16x4*)&c1b[(size_t)row * HD2 + idx];
  const float x0 = (float)v[0], x1 = (float)v[1], x2 = (float)v[2], x3 = (float)v[3];
  float s = x0 + x1 + x2 + x3;
  for (int o = 1; o < 64; o <<= 1) s += __shfl_xor(s, o);
  if (lane == 0) sred[rib][half][0] = s;
  __syncthreads();
  const float mu = (sred[rib][0][0] + sred[rib][1][0]) * (1.f / HD2);
  const float d0 = x0 - mu, d1 = x1 - mu, d2 = x2 - mu, d3 = x3 - mu;
  float q = d0 * d0 + d1 * d1 + d2 * d2 + d3 * d3;
  for (int o = 1; o < 64; o <<= 1) q += __shfl_xor(q, o);
  if (lane == 0) sred[rib][half][1] = q;
  __syncthreads();
  const float inv = rsqrtf((sred[rib][0][1] + sred[rib][1][1]) * (1.f / HD2) + 1e-5f);
  const float4 gv = *(const float4*)&g[idx];
  const float4 bv = *(const float4*)&b[idx];
  bf16x4 r;
  r[0] = (__bf16)fmaxf(d0 * inv * gv.x + bv.x, 0.f);
  r[1] = (__bf16)fmaxf(d1 * inv * gv.y + bv.y, 0.f);
  r[2] = (__bf16)fmaxf(d2 * inv * gv.z + bv.z, 0.f);
  r[3] = (__bf16)fmaxf(d3 * inv * gv.w + bv.w, 0.f);
  *(bf16x4*)&a2[(size_t)row * HD2 + idx] = r;
}

// ---------------- head: out = zb @ lin_w + lin_b (zb already relu(LN)) ----------------
__global__ __launch_bounds__(256)
void k_head(const __bf16* __restrict__ zb, const float* __restrict__ lw,
            const float* __restrict__ lb, float* __restrict__ out) {
  __shared__ float slw[256 * 16];     // [k][c]
  __shared__ __bf16 srow[16 * 256];
  const int t = threadIdx.x;
  const size_t row0 = (size_t)blockIdx.x * 16;
  #pragma unroll
  for (int j = 0; j < 16; j++) slw[j * 256 + t] = lw[j * 256 + t];
  #pragma unroll
  for (int j = 0; j < 2; j++) {
    const int c = j * 256 + t;
    ((bf16x8*)srow)[c] = ((const bf16x8*)(zb + row0 * 256))[c];
  }
  __syncthreads();
  const int rl = t >> 4, col = t & 15;
  float s = lb[col];
  for (int k0 = 0; k0 < 256; k0 += 8) {
    const bf16x8 zv = *(const bf16x8*)&srow[rl * 256 + k0];
    #pragma unroll
    for (int q = 0; q < 8; q++) s += (float)zv[q] * slw[(k0 + q) * 16 + col];
  }
  out[(row0 + rl) * 16 + col] = s;
}

// ---------------- host launch ----------------
extern "C" void kernel_launch(void* const* d_in, const int* in_sizes, int n_in,
                              void* d_out, int out_size, void* d_ws, size_t ws_size,
                              hipStream_t stream) {
  const float* x     = (const float*)d_in[0];
  const int*   ei    = (const int*)d_in[1];
  const float* ea    = (const float*)d_in[2];
  const float* enc_w = (const float*)d_in[3];
  const float* enc_b = (const float*)d_in[4];
  const float* ee_w  = (const float*)d_in[5];
  const float* ee_b  = (const float*)d_in[6];
  const float* w1    = (const float*)d_in[7];
  const float* b1    = (const float*)d_in[8];
  const float* lng   = (const float*)d_in[9];
  const float* lnb   = (const float*)d_in[10];
  const float* w2    = (const float*)d_in[11];
  const float* b2    = (const float*)d_in[12];
  const float* tvec  = (const float*)d_in[13];
  const float* ng    = (const float*)d_in[14];
  const float* nb    = (const float*)d_in[15];
  const float* lin_w = (const float*)d_in[16];
  const float* lin_b = (const float*)d_in[17];

  uint8_t* p = (uint8_t*)d_ws;
  auto alloc = [&](size_t bytes) { uint8_t* r = p; p += (bytes + 255) & ~(size_t)255; return r; };
  __bf16* e_bf   = (__bf16*)alloc((size_t)NE * HD * 2);
  float*  h      = (float*) alloc((size_t)NN * HD * 4);
  __bf16* hb     = (__bf16*)alloc((size_t)NN * HD * 2);
  __bf16* zb     = (__bf16*)alloc((size_t)NN * HD * 2);
  __bf16* a1     = (__bf16*)alloc((size_t)NN * HD * 2);
  __bf16* c1b    = (__bf16*)alloc((size_t)NN * HD2 * 2);
  __bf16* a2     = (__bf16*)alloc((size_t)NN * HD2 * 2);
  __bf16* xbf    = (__bf16*)alloc((size_t)NN * DIN * 2);
  __bf16* eabf   = (__bf16*)alloc((size_t)NE * DE * 2);
  __bf16* enc_wT = (__bf16*)alloc((size_t)HD * DIN * 2);
  __bf16* ee_wT  = (__bf16*)alloc((size_t)HD * DE * 2);
  __bf16* w1T    = (__bf16*)alloc((size_t)4 * HD2 * HD * 2);
  __bf16* w2T    = (__bf16*)alloc((size_t)4 * HD * HD2 * 2);
  int* deg       = (int*)alloc((size_t)NN * 4);
  int* cursor    = (int*)alloc((size_t)NN * 4);   // contiguous with deg -> one memset
  int* row_start = (int*)alloc((size_t)NN * 4);
  int2* csr_es   = (int2*)alloc((size_t)NE * 8);

  const int* srcp = ei;
  const int* dstp = ei + NE;

  hipMemsetAsync(deg, 0, (size_t)NN * 8, stream);  // deg + cursor
  k_hist<<<NE / 256, 256, 0, stream>>>(dstp, deg);
  k_scan<<<1, 1024, 0, stream>>>(deg, row_start);
  k_scatter<<<NE / 256, 256, 0, stream>>>(srcp, dstp, row_start, cursor, csr_es);
  k_sort<<<NN / 256, 256, 0, stream>>>(row_start, deg, csr_es);

  const int prep_total = DIN * HD + DE * HD + 4 * HD * HD2 + 4 * HD2 * HD +
                         NN * DIN / 4 + NE * DE / 4;
  k_prep<<<(prep_total + 255) / 256, 256, 0, stream>>>(enc_w, ee_w, w1, w2, x, ea,
                                                       enc_wT, ee_wT, w1T, w2T, xbf, eabf);

  // node encoder: h(f32) + hb(bf16) = x @ enc_w + enc_b  [M=16384, N=256, K=128]
  k_gemmL<128, 0, 2><<<(NN / 128) * (HD / 64), 256, 0, stream>>>(
      xbf, enc_wT, enc_b, nullptr, h, hb, HD);
  // edge encoder: e_bf = bf16(ea @ ee_w + ee_b)  [M=131072, N=256, K=64]
  k_gemmL<64, 0, 1><<<(NE / 128) * (HD / 64), 256, 0, stream>>>(
      eabf, ee_wT, ee_b, nullptr, nullptr, e_bf, HD);

  for (int i = 0; i < 4; i++) {
    const __bf16* zin = (i == 0) ? hb : zb;
    k_msg<<<NN / 4, 256, 0, stream>>>(zin, e_bf, row_start, deg, csr_es, tvec, i, a1);
    // GEMM1: c1b = bf16(a1 @ w1 + b1)  [N=512, K=256]
    k_gemmL<256, 0, 1><<<(NN / 128) * (HD2 / 64), 256, 0, stream>>>(
        a1, w1T + (size_t)i * HD2 * HD, b1 + (size_t)i * HD2, nullptr, nullptr, c1b, HD2);
    // LN512 + ReLU -> a2
    k_ln512<<<NN / 2, 256, 0, stream>>>(c1b, lng + (size_t)i * HD2, lnb + (size_t)i * HD2, a2);
    // GEMM2: h = a2 @ w2 + b2 (+h residual)  [N=256, K=512]
    if (i == 0)
      k_gemmL<512, 0, 0><<<(NN / 128) * (HD / 64), 256, 0, stream>>>(
          a2, w2T + (size_t)i * HD * HD2, b2 + (size_t)i * HD, nullptr, h, nullptr, HD);
    else
      k_gemmL<512, 1, 0><<<(NN / 128) * (HD / 64), 256, 0, stream>>>(
          a2, w2T + (size_t)i * HD * HD2, b2 + (size_t)i * HD, h, h, nullptr, HD);
    // pre-norm for next layer (ng[i+1]) or final LN (ng[0])
    const int nidx = (i < 3) ? i + 1 : 0;
    k_prenorm<<<NN / 4, 256, 0, stream>>>(h, ng + (size_t)nidx * HD, nb + (size_t)nidx * HD, zb);
  }

  k_head<<<NN / 16, 256, 0, stream>>>(zb, lin_w, lin_b, (float*)d_out);
}

// Round 6
// 425.123 us; speedup vs baseline: 1.0973x; 1.0973x over previous
//
#include <hip/hip_runtime.h>
#include <stdint.h>
#include <math.h>

// DeeperGNN forward on MI355X.
// R6: validated R2 k_gemm K-loop + NEW coalesced epilogue (LDS-transposed stores).
// encoders -> per layer { msg aggregation -> GEMM1 -> LN512 -> GEMM2(+res) -> preLN }
// -> head. f32 residual/LN stats; bf16 GEMM operands + edge encodings.

typedef __bf16 bf16x8 __attribute__((ext_vector_type(8)));
typedef __bf16 bf16x4 __attribute__((ext_vector_type(4)));
typedef float  f32x4  __attribute__((ext_vector_type(4)));

constexpr int NN   = 16384;   // nodes
constexpr int NE   = 131072;  // edges
constexpr int DIN  = 128;
constexpr int DE   = 64;
constexpr int HD   = 256;
constexpr int HD2  = 512;

__device__ __forceinline__ void gl_lds16(const __bf16* g, __bf16* l) {
  __builtin_amdgcn_global_load_lds((const __attribute__((address_space(1))) void*)g,
                                   (__attribute__((address_space(3))) void*)l, 16, 0, 0);
}

// ---------------- CSR build ----------------
__global__ void k_hist(const int* __restrict__ dst, int* __restrict__ deg) {
  int e = blockIdx.x * 256 + threadIdx.x;
  if (e < NE) atomicAdd(&deg[dst[e]], 1);
}

__global__ __launch_bounds__(1024) void k_scan(const int* __restrict__ deg,
                                               int* __restrict__ row_start) {
  __shared__ int part[1024];
  const int t = threadIdx.x;
  const int base = t * 16;
  int loc[16];
  int s = 0;
  #pragma unroll
  for (int i = 0; i < 16; i++) { loc[i] = s; s += deg[base + i]; }
  part[t] = s;
  __syncthreads();
  for (int off = 1; off < 1024; off <<= 1) {
    int v = (t >= off) ? part[t - off] : 0;
    __syncthreads();
    part[t] += v;
    __syncthreads();
  }
  const int excl = (t == 0) ? 0 : part[t - 1];
  #pragma unroll
  for (int i = 0; i < 16; i++) row_start[base + i] = excl + loc[i];
}

__global__ void k_scatter(const int* __restrict__ src, const int* __restrict__ dst,
                          const int* __restrict__ row_start, int* __restrict__ cursor,
                          int2* __restrict__ csr_es) {
  int e = blockIdx.x * 256 + threadIdx.x;
  if (e >= NE) return;
  const int d = dst[e];
  const int p = atomicAdd(&cursor[d], 1);
  csr_es[row_start[d] + p] = make_int2(e, src[e]);
}

// canonical per-node eid-order (determinism); one thread per node, deg ~8
__global__ void k_sort(const int* __restrict__ row_start, const int* __restrict__ deg,
                       int2* __restrict__ csr_es) {
  int n = blockIdx.x * 256 + threadIdx.x;
  if (n >= NN) return;
  const int st = row_start[n], dg = deg[n];
  for (int a = 1; a < dg; a++) {
    int2 k = csr_es[st + a];
    int b = a - 1;
    while (b >= 0 && csr_es[st + b].x > k.x) { csr_es[st + b + 1] = csr_es[st + b]; b--; }
    csr_es[st + b + 1] = k;
  }
}

// ---------------- merged prep: weight transposes + input bf16 casts ----------------
__global__ void k_prep(const float* __restrict__ enc_w, const float* __restrict__ ee_w,
                       const float* __restrict__ w1, const float* __restrict__ w2,
                       const float* __restrict__ x, const float* __restrict__ ea,
                       __bf16* __restrict__ enc_wT, __bf16* __restrict__ ee_wT,
                       __bf16* __restrict__ w1T, __bf16* __restrict__ w2T,
                       __bf16* __restrict__ xbf, __bf16* __restrict__ eabf) {
  int i = blockIdx.x * 256 + threadIdx.x;
  const int S0 = DIN * HD, S1 = DE * HD, S2 = 4 * HD * HD2, S3 = 4 * HD2 * HD;
  const int S4 = NN * DIN / 4, S5 = NE * DE / 4;
  if (i < S0) { int k = i / HD, n = i % HD; enc_wT[n * DIN + k] = (__bf16)enc_w[i]; return; }
  i -= S0;
  if (i < S1) { int k = i / HD, n = i % HD; ee_wT[n * DE + k] = (__bf16)ee_w[i]; return; }
  i -= S1;
  if (i < S2) {
    int l = i / (HD * HD2), r = i % (HD * HD2), k = r / HD2, n = r % HD2;
    w1T[(size_t)l * HD * HD2 + (size_t)n * HD + k] = (__bf16)w1[i]; return;
  }
  i -= S2;
  if (i < S3) {
    int l = i / (HD2 * HD), r = i % (HD2 * HD), k = r / HD, n = r % HD;
    w2T[(size_t)l * HD2 * HD + (size_t)n * HD2 + k] = (__bf16)w2[i]; return;
  }
  i -= S3;
  if (i < S4) {
    float4 v = ((const float4*)x)[i];
    bf16x4 r; r[0] = (__bf16)v.x; r[1] = (__bf16)v.y; r[2] = (__bf16)v.z; r[3] = (__bf16)v.w;
    ((bf16x4*)xbf)[i] = r; return;
  }
  i -= S4;
  if (i < S5) {
    float4 v = ((const float4*)ea)[i];
    bf16x4 r; r[0] = (__bf16)v.x; r[1] = (__bf16)v.y; r[2] = (__bf16)v.z; r[3] = (__bf16)v.w;
    ((bf16x4*)eabf)[i] = r; return;
  }
}

// ---------------- MFMA GEMM, 128x128 tile, coalesced epilogue ----------------
// C[M,Nn] = A[M,K](bf16) * BT[Nn,K](bf16) + bias (+R).
// K-loop: R2-validated structure (gl_lds stage -> barrier -> ds_read+MFMA -> barrier).
// Epilogue: per 32-row slice, scatter acc f32 -> sm LDS, read back row-major,
// add bias/residual, emit 32-64B/lane coalesced stores.
// OBF: 0=f32 Cf, 1=bf16 Cb, 2=dual (f32 Cf + bf16 Cb).
template <int RES, int OBF>
__global__ __launch_bounds__(256, 2)
void k_gemm(const __bf16* __restrict__ A, const __bf16* __restrict__ BT,
            const float* __restrict__ bias, const float* __restrict__ R,
            float* __restrict__ Cf, __bf16* __restrict__ Cb, int M, int Nn, int K) {
  __shared__ __bf16 lsA[4096];
  __shared__ __bf16 lsB[4096];
  __shared__ float sm[32][132];   // +4 pad: 16B-aligned rows, spread banks
  __shared__ float sbias[128];
  const int tid  = threadIdx.x;
  const int lane = tid & 63;
  const int wave = tid >> 6;
  const int ntn  = Nn >> 7;
  const int bm   = (int)blockIdx.x / ntn;
  const int bn   = (int)blockIdx.x % ntn;
  const size_t row0 = (size_t)bm * 128, col0 = (size_t)bn * 128;
  const int wr = (wave >> 1) * 64, wc = (wave & 1) * 64;
  const int ks = lane >> 4, fr = lane & 15;

  f32x4 acc[4][4] = {};

  const int s1 = tid, s2 = tid + 256;
  const int r1 = s1 & 127, ks1 = s1 >> 7;
  const int r2 = s2 & 127, ks2 = s2 >> 7;

  for (int k0 = 0; k0 < K; k0 += 32) {
    gl_lds16(A  + (row0 + r1) * K + k0 + ks1 * 8, &lsA[s1 * 8]);
    gl_lds16(A  + (row0 + r2) * K + k0 + ks2 * 8, &lsA[s2 * 8]);
    gl_lds16(BT + (col0 + r1) * K + k0 + ks1 * 8, &lsB[s1 * 8]);
    gl_lds16(BT + (col0 + r2) * K + k0 + ks2 * 8, &lsB[s2 * 8]);
    __syncthreads();
    bf16x8 af[4], bfr[4];
    #pragma unroll
    for (int m = 0; m < 4; m++) af[m]  = *(const bf16x8*)&lsA[(ks * 128 + wr + m * 16 + fr) * 8];
    #pragma unroll
    for (int n = 0; n < 4; n++) bfr[n] = *(const bf16x8*)&lsB[(ks * 128 + wc + n * 16 + fr) * 8];
    #pragma unroll
    for (int m = 0; m < 4; m++)
      #pragma unroll
      for (int n = 0; n < 4; n++)
        acc[m][n] = __builtin_amdgcn_mfma_f32_16x16x32_bf16(af[m], bfr[n], acc[m][n], 0, 0, 0);
    __syncthreads();
  }

  // ---- coalesced epilogue ----
  if (tid < 128) sbias[tid] = bias[col0 + tid];
  const int fq = ks;
  const int rbase = (wave >> 1) * 16 + fq * 4;   // scatter row base within slice
  const int rr = tid >> 3, cs = (tid & 7) * 16;  // readback: 32 rows x 8 chunks
  #pragma unroll
  for (int m = 0; m < 4; m++) {
    if (m) __syncthreads();   // protect sm reuse across slices
    #pragma unroll
    for (int n = 0; n < 4; n++)
      #pragma unroll
      for (int r = 0; r < 4; r++)
        sm[rbase + r][wc + n * 16 + fr] = acc[m][n][r];
    __syncthreads();
    const size_t grow = row0 + ((rr & 16) ? 64 : 0) + m * 16 + (rr & 15);
    const size_t gbase = grow * Nn + col0 + cs;
    float v[16];
    #pragma unroll
    for (int j = 0; j < 16; j++) v[j] = sm[rr][cs + j] + sbias[cs + j];
    if (RES) {
      #pragma unroll
      for (int j = 0; j < 16; j += 4) {
        const float4 rv = *(const float4*)&R[gbase + j];
        v[j] += rv.x; v[j + 1] += rv.y; v[j + 2] += rv.z; v[j + 3] += rv.w;
      }
    }
    if (OBF == 0 || OBF == 2) {
      #pragma unroll
      for (int j = 0; j < 16; j += 4) {
        float4 o; o.x = v[j]; o.y = v[j + 1]; o.z = v[j + 2]; o.w = v[j + 3];
        *(float4*)&Cf[gbase + j] = o;
      }
    }
    if (OBF == 1 || OBF == 2) {
      bf16x8 o0, o1;
      #pragma unroll
      for (int j = 0; j < 8; j++) { o0[j] = (__bf16)v[j]; o1[j] = (__bf16)v[8 + j]; }
      *(bf16x8*)&Cb[gbase] = o0;
      *(bf16x8*)&Cb[gbase + 8] = o1;
    }
  }
}

// ---------------- wave-per-node softmax aggregation ----------------
// 4-edge load groups: 8 gathers in flight before consumption (latency hiding).
__global__ __launch_bounds__(256)
void k_msg(const __bf16* __restrict__ zb, const __bf16* __restrict__ ebf,
           const int* __restrict__ row_start, const int* __restrict__ deg,
           const int2* __restrict__ csr_es, const float* __restrict__ tvec,
           int layer, __bf16* __restrict__ a1) {
  const int wv   = __builtin_amdgcn_readfirstlane(threadIdx.x >> 6);
  const int lane = threadIdx.x & 63;
  const int node = blockIdx.x * 4 + wv;
  const int st = __builtin_amdgcn_readfirstlane(row_start[node]);
  const int dg = __builtin_amdgcn_readfirstlane(deg[node]);
  const float t = tvec[layer];
  const int f0 = lane * 4;

  int my_eid = 0, my_src = 0;
  if (lane < dg) { int2 pr = csr_es[st + lane]; my_eid = pr.x; my_src = pr.y; }

  float den[4] = {0.f, 0.f, 0.f, 0.f}, agg[4] = {0.f, 0.f, 0.f, 0.f};
  const int dmain = dg < 64 ? dg : 64;
  int j = 0;
  for (; j + 4 <= dmain; j += 4) {
    bf16x4 zv[4], ev[4];
    #pragma unroll
    for (int u = 0; u < 4; u++) {
      const int eid = __builtin_amdgcn_readlane(my_eid, j + u);
      const int sn  = __builtin_amdgcn_readlane(my_src, j + u);
      zv[u] = *(const bf16x4*)&zb[(size_t)sn * HD + f0];
      ev[u] = *(const bf16x4*)&ebf[(size_t)eid * HD + f0];
    }
    #pragma unroll
    for (int u = 0; u < 4; u++)
      #pragma unroll
      for (int q = 0; q < 4; q++) {
        const float m  = fmaxf((float)zv[u][q] + (float)ev[u][q], 0.f) + 1e-7f;
        const float ex = __expf(m * t);
        den[q] += ex;
        agg[q] += m * ex;
      }
  }
  for (; j < dmain; j++) {
    const int eid = __builtin_amdgcn_readlane(my_eid, j);
    const int sn  = __builtin_amdgcn_readlane(my_src, j);
    const bf16x4 zv = *(const bf16x4*)&zb[(size_t)sn * HD + f0];
    const bf16x4 ev = *(const bf16x4*)&ebf[(size_t)eid * HD + f0];
    #pragma unroll
    for (int q = 0; q < 4; q++) {
      const float m  = fmaxf((float)zv[q] + (float)ev[q], 0.f) + 1e-7f;
      const float ex = __expf(m * t);
      den[q] += ex;
      agg[q] += m * ex;
    }
  }
  for (int jj = 64; jj < dg; jj++) {  // cold path
    const int2 pr = csr_es[st + jj];
    const bf16x4 zv = *(const bf16x4*)&zb[(size_t)pr.y * HD + f0];
    const bf16x4 ev = *(const bf16x4*)&ebf[(size_t)pr.x * HD + f0];
    #pragma unroll
    for (int q = 0; q < 4; q++) {
      const float m  = fmaxf((float)zv[q] + (float)ev[q], 0.f) + 1e-7f;
      const float ex = __expf(m * t);
      den[q] += ex;
      agg[q] += m * ex;
    }
  }
  const bf16x4 sv = *(const bf16x4*)&zb[(size_t)node * HD + f0];
  bf16x4 r;
  #pragma unroll
  for (int q = 0; q < 4; q++) {
    const float res = (dg > 0) ? agg[q] / (den[q] + 1e-16f) : 0.f;
    r[q] = (__bf16)(res + (float)sv[q]);
  }
  *(bf16x4*)&a1[(size_t)node * HD + f0] = r;
}

// ---------------- LN kernels ----------------
// zb = bf16(relu(LN_256(h))). 4 rows/block, 64 lanes x 4 feats.
__global__ __launch_bounds__(256)
void k_prenorm(const float* __restrict__ h, const float* __restrict__ g,
               const float* __restrict__ b, __bf16* __restrict__ zb) {
  const int row  = blockIdx.x * 4 + (threadIdx.x >> 6);
  const int lane = threadIdx.x & 63;
  const float4 v = *(const float4*)&h[(size_t)row * HD + lane * 4];
  float s = v.x + v.y + v.z + v.w;
  for (int o = 1; o < 64; o <<= 1) s += __shfl_xor(s, o);
  const float mu = s * (1.f / HD);
  const float dx = v.x - mu, dy = v.y - mu, dz = v.z - mu, dw = v.w - mu;
  float q = dx * dx + dy * dy + dz * dz + dw * dw;
  for (int o = 1; o < 64; o <<= 1) q += __shfl_xor(q, o);
  const float inv = rsqrtf(q * (1.f / HD) + 1e-5f);
  const float4 gv = *(const float4*)&g[lane * 4];
  const float4 bv = *(const float4*)&b[lane * 4];
  bf16x4 r;
  r[0] = (__bf16)fmaxf(dx * inv * gv.x + bv.x, 0.f);
  r[1] = (__bf16)fmaxf(dy * inv * gv.y + bv.y, 0.f);
  r[2] = (__bf16)fmaxf(dz * inv * gv.z + bv.z, 0.f);
  r[3] = (__bf16)fmaxf(dw * inv * gv.w + bv.w, 0.f);
  *(bf16x4*)&zb[(size_t)row * HD + lane * 4] = r;
}

// a2 = bf16(relu(LN_512(c1b))), 2 rows/block, 2 waves/row, bf16x4/lane.
__global__ __launch_bounds__(256)
void k_ln512(const __bf16* __restrict__ c1b, const float* __restrict__ g,
             const float* __restrict__ b, __bf16* __restrict__ a2) {
  __shared__ float sred[2][2][2];
  const int tid = threadIdx.x, lane = tid & 63, wv = tid >> 6;
  const int rib = wv >> 1, half = wv & 1;
  const int row = blockIdx.x * 2 + rib;
  const int idx = (half * 64 + lane) * 4;
  const bf16x4 v = *(const bf16x4*)&c1b[(size_t)row * HD2 + idx];
  const float x0 = (float)v[0], x1 = (float)v[1], x2 = (float)v[2], x3 = (float)v[3];
  float s = x0 + x1 + x2 + x3;
  for (int o = 1; o < 64; o <<= 1) s += __shfl_xor(s, o);
  if (lane == 0) sred[rib][half][0] = s;
  __syncthreads();
  const float mu = (sred[rib][0][0] + sred[rib][1][0]) * (1.f / HD2);
  const float d0 = x0 - mu, d1 = x1 - mu, d2 = x2 - mu, d3 = x3 - mu;
  float q = d0 * d0 + d1 * d1 + d2 * d2 + d3 * d3;
  for (int o = 1; o < 64; o <<= 1) q += __shfl_xor(q, o);
  if (lane == 0) sred[rib][half][1] = q;
  __syncthreads();
  const float inv = rsqrtf((sred[rib][0][1] + sred[rib][1][1]) * (1.f / HD2) + 1e-5f);
  const float4 gv = *(const float4*)&g[idx];
  const float4 bv = *(const float4*)&b[idx];
  bf16x4 r;
  r[0] = (__bf16)fmaxf(d0 * inv * gv.x + bv.x, 0.f);
  r[1] = (__bf16)fmaxf(d1 * inv * gv.y + bv.y, 0.f);
  r[2] = (__bf16)fmaxf(d2 * inv * gv.z + bv.z, 0.f);
  r[3] = (__bf16)fmaxf(d3 * inv * gv.w + bv.w, 0.f);
  *(bf16x4*)&a2[(size_t)row * HD2 + idx] = r;
}

// ---------------- head: out = zb @ lin_w + lin_b (zb already relu(LN)) ----------------
__global__ __launch_bounds__(256)
void k_head(const __bf16* __restrict__ zb, const float* __restrict__ lw,
            const float* __restrict__ lb, float* __restrict__ out) {
  __shared__ float slw[256 * 16];     // [k][c]
  __shared__ __bf16 srow[16 * 256];
  const int t = threadIdx.x;
  const size_t row0 = (size_t)blockIdx.x * 16;
  #pragma unroll
  for (int j = 0; j < 16; j++) slw[j * 256 + t] = lw[j * 256 + t];
  #pragma unroll
  for (int j = 0; j < 2; j++) {
    const int c = j * 256 + t;
    ((bf16x8*)srow)[c] = ((const bf16x8*)(zb + row0 * 256))[c];
  }
  __syncthreads();
  const int rl = t >> 4, col = t & 15;
  float s = lb[col];
  for (int k0 = 0; k0 < 256; k0 += 8) {
    const bf16x8 zv = *(const bf16x8*)&srow[rl * 256 + k0];
    #pragma unroll
    for (int q = 0; q < 8; q++) s += (float)zv[q] * slw[(k0 + q) * 16 + col];
  }
  out[(row0 + rl) * 16 + col] = s;
}

// ---------------- host launch ----------------
extern "C" void kernel_launch(void* const* d_in, const int* in_sizes, int n_in,
                              void* d_out, int out_size, void* d_ws, size_t ws_size,
                              hipStream_t stream) {
  const float* x     = (const float*)d_in[0];
  const int*   ei    = (const int*)d_in[1];
  const float* ea    = (const float*)d_in[2];
  const float* enc_w = (const float*)d_in[3];
  const float* enc_b = (const float*)d_in[4];
  const float* ee_w  = (const float*)d_in[5];
  const float* ee_b  = (const float*)d_in[6];
  const float* w1    = (const float*)d_in[7];
  const float* b1    = (const float*)d_in[8];
  const float* lng   = (const float*)d_in[9];
  const float* lnb   = (const float*)d_in[10];
  const float* w2    = (const float*)d_in[11];
  const float* b2    = (const float*)d_in[12];
  const float* tvec  = (const float*)d_in[13];
  const float* ng    = (const float*)d_in[14];
  const float* nb    = (const float*)d_in[15];
  const float* lin_w = (const float*)d_in[16];
  const float* lin_b = (const float*)d_in[17];

  uint8_t* p = (uint8_t*)d_ws;
  auto alloc = [&](size_t bytes) { uint8_t* r = p; p += (bytes + 255) & ~(size_t)255; return r; };
  __bf16* e_bf   = (__bf16*)alloc((size_t)NE * HD * 2);
  float*  h      = (float*) alloc((size_t)NN * HD * 4);
  __bf16* hb     = (__bf16*)alloc((size_t)NN * HD * 2);
  __bf16* zb     = (__bf16*)alloc((size_t)NN * HD * 2);
  __bf16* a1     = (__bf16*)alloc((size_t)NN * HD * 2);
  __bf16* c1b    = (__bf16*)alloc((size_t)NN * HD2 * 2);
  __bf16* a2     = (__bf16*)alloc((size_t)NN * HD2 * 2);
  __bf16* xbf    = (__bf16*)alloc((size_t)NN * DIN * 2);
  __bf16* eabf   = (__bf16*)alloc((size_t)NE * DE * 2);
  __bf16* enc_wT = (__bf16*)alloc((size_t)HD * DIN * 2);
  __bf16* ee_wT  = (__bf16*)alloc((size_t)HD * DE * 2);
  __bf16* w1T    = (__bf16*)alloc((size_t)4 * HD2 * HD * 2);
  __bf16* w2T    = (__bf16*)alloc((size_t)4 * HD * HD2 * 2);
  int* deg       = (int*)alloc((size_t)NN * 4);
  int* cursor    = (int*)alloc((size_t)NN * 4);   // contiguous with deg -> one memset
  int* row_start = (int*)alloc((size_t)NN * 4);
  int2* csr_es   = (int2*)alloc((size_t)NE * 8);

  const int* srcp = ei;
  const int* dstp = ei + NE;

  hipMemsetAsync(deg, 0, (size_t)NN * 8, stream);  // deg + cursor
  k_hist<<<NE / 256, 256, 0, stream>>>(dstp, deg);
  k_scan<<<1, 1024, 0, stream>>>(deg, row_start);
  k_scatter<<<NE / 256, 256, 0, stream>>>(srcp, dstp, row_start, cursor, csr_es);
  k_sort<<<NN / 256, 256, 0, stream>>>(row_start, deg, csr_es);

  const int prep_total = DIN * HD + DE * HD + 4 * HD * HD2 + 4 * HD2 * HD +
                         NN * DIN / 4 + NE * DE / 4;
  k_prep<<<(prep_total + 255) / 256, 256, 0, stream>>>(enc_w, ee_w, w1, w2, x, ea,
                                                       enc_wT, ee_wT, w1T, w2T, xbf, eabf);

  // node encoder: h(f32) + hb(bf16) = x @ enc_w + enc_b  [M=16384, N=256, K=128]
  k_gemm<0, 2><<<(NN / 128) * (HD / 128), 256, 0, stream>>>(
      xbf, enc_wT, enc_b, nullptr, h, hb, NN, HD, DIN);
  // edge encoder: e_bf = bf16(ea @ ee_w + ee_b)  [M=131072, N=256, K=64]
  k_gemm<0, 1><<<(NE / 128) * (HD / 128), 256, 0, stream>>>(
      eabf, ee_wT, ee_b, nullptr, nullptr, e_bf, NE, HD, DE);

  for (int i = 0; i < 4; i++) {
    const __bf16* zin = (i == 0) ? hb : zb;
    k_msg<<<NN / 4, 256, 0, stream>>>(zin, e_bf, row_start, deg, csr_es, tvec, i, a1);
    // GEMM1: c1b = bf16(a1 @ w1 + b1)  [N=512, K=256]
    k_gemm<0, 1><<<(NN / 128) * (HD2 / 128), 256, 0, stream>>>(
        a1, w1T + (size_t)i * HD2 * HD, b1 + (size_t)i * HD2, nullptr, nullptr, c1b,
        NN, HD2, HD);
    // LN512 + ReLU -> a2
    k_ln512<<<NN / 2, 256, 0, stream>>>(c1b, lng + (size_t)i * HD2, lnb + (size_t)i * HD2, a2);
    // GEMM2: h = a2 @ w2 + b2 (+h residual)  [N=256, K=512]
    if (i == 0)
      k_gemm<0, 0><<<(NN / 128) * (HD / 128), 256, 0, stream>>>(
          a2, w2T + (size_t)i * HD * HD2, b2 + (size_t)i * HD, nullptr, h, nullptr,
          NN, HD, HD2);
    else
      k_gemm<1, 0><<<(NN / 128) * (HD / 128), 256, 0, stream>>>(
          a2, w2T + (size_t)i * HD * HD2, b2 + (size_t)i * HD, h, h, nullptr,
          NN, HD, HD2);
    // pre-norm for next layer (ng[i+1]) or final LN (ng[0])
    const int nidx = (i < 3) ? i + 1 : 0;
    k_prenorm<<<NN / 4, 256, 0, stream>>>(h, ng + (size_t)nidx * HD, nb + (size_t)nidx * HD, zb);
  }

  k_head<<<NN / 16, 256, 0, stream>>>(zb, lin_w, lin_b, (float*)d_out);
}

// Round 7
// 409.805 us; speedup vs baseline: 1.1383x; 1.0374x over previous
//
#include <hip/hip_runtime.h>
#include <stdint.h>
#include <math.h>

// DeeperGNN forward on MI355X.
// R7: CSR-ordered edge encodings (sequential k_msg e-reads), ln512 fused into
// gemm2 A-staging via pstats, final prenorm+head fused. 24 launches.

typedef __bf16 bf16x8 __attribute__((ext_vector_type(8)));
typedef __bf16 bf16x4 __attribute__((ext_vector_type(4)));
typedef float  f32x4  __attribute__((ext_vector_type(4)));

constexpr int NN   = 16384;   // nodes
constexpr int NE   = 131072;  // edges
constexpr int DIN  = 128;
constexpr int DE   = 64;
constexpr int HD   = 256;
constexpr int HD2  = 512;

__device__ __forceinline__ void gl_lds16(const __bf16* g, __bf16* l) {
  __builtin_amdgcn_global_load_lds((const __attribute__((address_space(1))) void*)g,
                                   (__attribute__((address_space(3))) void*)l, 16, 0, 0);
}

// ---------------- CSR build ----------------
__global__ void k_hist(const int* __restrict__ dst, int* __restrict__ deg) {
  int e = blockIdx.x * 256 + threadIdx.x;
  if (e < NE) atomicAdd(&deg[dst[e]], 1);
}

__global__ __launch_bounds__(1024) void k_scan(const int* __restrict__ deg,
                                               int* __restrict__ row_start) {
  __shared__ int part[1024];
  const int t = threadIdx.x;
  const int base = t * 16;
  int loc[16];
  int s = 0;
  #pragma unroll
  for (int i = 0; i < 16; i++) { loc[i] = s; s += deg[base + i]; }
  part[t] = s;
  __syncthreads();
  for (int off = 1; off < 1024; off <<= 1) {
    int v = (t >= off) ? part[t - off] : 0;
    __syncthreads();
    part[t] += v;
    __syncthreads();
  }
  const int excl = (t == 0) ? 0 : part[t - 1];
  #pragma unroll
  for (int i = 0; i < 16; i++) row_start[base + i] = excl + loc[i];
}

__global__ void k_scatter(const int* __restrict__ src, const int* __restrict__ dst,
                          const int* __restrict__ row_start, int* __restrict__ cursor,
                          int2* __restrict__ csr_es) {
  int e = blockIdx.x * 256 + threadIdx.x;
  if (e >= NE) return;
  const int d = dst[e];
  const int p = atomicAdd(&cursor[d], 1);
  csr_es[row_start[d] + p] = make_int2(e, src[e]);
}

// canonical per-node eid-order (determinism) + posmap[eid] = CSR position
__global__ void k_sort(const int* __restrict__ row_start, const int* __restrict__ deg,
                       int2* __restrict__ csr_es, int* __restrict__ posmap) {
  int n = blockIdx.x * 256 + threadIdx.x;
  if (n >= NN) return;
  const int st = row_start[n], dg = deg[n];
  for (int a = 1; a < dg; a++) {
    int2 k = csr_es[st + a];
    int b = a - 1;
    while (b >= 0 && csr_es[st + b].x > k.x) { csr_es[st + b + 1] = csr_es[st + b]; b--; }
    csr_es[st + b + 1] = k;
  }
  for (int a = 0; a < dg; a++) posmap[csr_es[st + a].x] = st + a;
}

// ---------------- merged prep: weight transposes + input bf16 casts ----------------
__global__ void k_prep(const float* __restrict__ enc_w, const float* __restrict__ ee_w,
                       const float* __restrict__ w1, const float* __restrict__ w2,
                       const float* __restrict__ x, const float* __restrict__ ea,
                       __bf16* __restrict__ enc_wT, __bf16* __restrict__ ee_wT,
                       __bf16* __restrict__ w1T, __bf16* __restrict__ w2T,
                       __bf16* __restrict__ xbf, __bf16* __restrict__ eabf) {
  int i = blockIdx.x * 256 + threadIdx.x;
  const int S0 = DIN * HD, S1 = DE * HD, S2 = 4 * HD * HD2, S3 = 4 * HD2 * HD;
  const int S4 = NN * DIN / 4, S5 = NE * DE / 4;
  if (i < S0) { int k = i / HD, n = i % HD; enc_wT[n * DIN + k] = (__bf16)enc_w[i]; return; }
  i -= S0;
  if (i < S1) { int k = i / HD, n = i % HD; ee_wT[n * DE + k] = (__bf16)ee_w[i]; return; }
  i -= S1;
  if (i < S2) {
    int l = i / (HD * HD2), r = i % (HD * HD2), k = r / HD2, n = r % HD2;
    w1T[(size_t)l * HD * HD2 + (size_t)n * HD + k] = (__bf16)w1[i]; return;
  }
  i -= S2;
  if (i < S3) {
    int l = i / (HD2 * HD), r = i % (HD2 * HD), k = r / HD, n = r % HD;
    w2T[(size_t)l * HD2 * HD + (size_t)n * HD2 + k] = (__bf16)w2[i]; return;
  }
  i -= S3;
  if (i < S4) {
    float4 v = ((const float4*)x)[i];
    bf16x4 r; r[0] = (__bf16)v.x; r[1] = (__bf16)v.y; r[2] = (__bf16)v.z; r[3] = (__bf16)v.w;
    ((bf16x4*)xbf)[i] = r; return;
  }
  i -= S4;
  if (i < S5) {
    float4 v = ((const float4*)ea)[i];
    bf16x4 r; r[0] = (__bf16)v.x; r[1] = (__bf16)v.y; r[2] = (__bf16)v.z; r[3] = (__bf16)v.w;
    ((bf16x4*)eabf)[i] = r; return;
  }
}

// ---------------- MFMA GEMM, 128x128 tile, coalesced epilogue ----------------
// OBF: 0=f32 Cf, 1=bf16 Cb, 2=dual. STATS: write per-row (sum,sumsq) partials
// to pstats[row][ntn] (f32, pre-bf16-round, bias included). ESCAT: Cb row
// remapped through posmap (CSR-ordered edge encodings).
template <int RES, int OBF, int STATS, int ESCAT>
__global__ __launch_bounds__(256, 2)
void k_gemm(const __bf16* __restrict__ A, const __bf16* __restrict__ BT,
            const float* __restrict__ bias, const float* __restrict__ R,
            float* __restrict__ Cf, __bf16* __restrict__ Cb,
            const int* __restrict__ posmap, float2* __restrict__ pstats,
            int M, int Nn, int K) {
  __shared__ __bf16 lsA[4096];
  __shared__ __bf16 lsB[4096];
  __shared__ float sm[32][132];
  __shared__ float sbias[128];
  __shared__ float2 pst4[4][32];
  const int tid  = threadIdx.x;
  const int lane = tid & 63;
  const int wave = tid >> 6;
  const int ntn  = Nn >> 7;
  const int bm   = (int)blockIdx.x / ntn;
  const int bn   = (int)blockIdx.x % ntn;
  const size_t row0 = (size_t)bm * 128, col0 = (size_t)bn * 128;
  const int wr = (wave >> 1) * 64, wc = (wave & 1) * 64;
  const int ks = lane >> 4, fr = lane & 15;

  f32x4 acc[4][4] = {};

  const int s1 = tid, s2 = tid + 256;
  const int r1 = s1 & 127, ks1 = s1 >> 7;
  const int r2 = s2 & 127, ks2 = s2 >> 7;

  for (int k0 = 0; k0 < K; k0 += 32) {
    gl_lds16(A  + (row0 + r1) * K + k0 + ks1 * 8, &lsA[s1 * 8]);
    gl_lds16(A  + (row0 + r2) * K + k0 + ks2 * 8, &lsA[s2 * 8]);
    gl_lds16(BT + (col0 + r1) * K + k0 + ks1 * 8, &lsB[s1 * 8]);
    gl_lds16(BT + (col0 + r2) * K + k0 + ks2 * 8, &lsB[s2 * 8]);
    __syncthreads();
    bf16x8 af[4], bfr[4];
    #pragma unroll
    for (int m = 0; m < 4; m++) af[m]  = *(const bf16x8*)&lsA[(ks * 128 + wr + m * 16 + fr) * 8];
    #pragma unroll
    for (int n = 0; n < 4; n++) bfr[n] = *(const bf16x8*)&lsB[(ks * 128 + wc + n * 16 + fr) * 8];
    #pragma unroll
    for (int m = 0; m < 4; m++)
      #pragma unroll
      for (int n = 0; n < 4; n++)
        acc[m][n] = __builtin_amdgcn_mfma_f32_16x16x32_bf16(af[m], bfr[n], acc[m][n], 0, 0, 0);
    __syncthreads();
  }

  // ---- coalesced epilogue (LDS-transposed) ----
  if (tid < 128) sbias[tid] = bias[col0 + tid];
  const int fq = ks;
  const int rbase = (wave >> 1) * 16 + fq * 4;
  const int rr = tid >> 3, cs = (tid & 7) * 16;
  #pragma unroll
  for (int m = 0; m < 4; m++) {
    if (m) __syncthreads();
    #pragma unroll
    for (int n = 0; n < 4; n++)
      #pragma unroll
      for (int r = 0; r < 4; r++)
        sm[rbase + r][wc + n * 16 + fr] = acc[m][n][r];
    __syncthreads();
    const size_t lrow = ((rr & 16) ? 64 : 0) + m * 16 + (rr & 15);
    const size_t grow = row0 + lrow;
    float v[16];
    #pragma unroll
    for (int j = 0; j < 16; j++) v[j] = sm[rr][cs + j] + sbias[cs + j];
    if (STATS) {
      float ssum = 0.f, ssq = 0.f;
      #pragma unroll
      for (int j = 0; j < 16; j++) { ssum += v[j]; ssq += v[j] * v[j]; }
      #pragma unroll
      for (int o = 1; o < 8; o <<= 1) {
        ssum += __shfl_xor(ssum, o);
        ssq  += __shfl_xor(ssq, o);
      }
      if ((tid & 7) == 0) pst4[m][rr].x = ssum, pst4[m][rr].y = ssq;
    }
    const size_t gbase = grow * Nn + col0 + cs;
    if (RES) {
      #pragma unroll
      for (int j = 0; j < 16; j += 4) {
        const float4 rv = *(const float4*)&R[gbase + j];
        v[j] += rv.x; v[j + 1] += rv.y; v[j + 2] += rv.z; v[j + 3] += rv.w;
      }
    }
    if (OBF == 0 || OBF == 2) {
      #pragma unroll
      for (int j = 0; j < 16; j += 4) {
        float4 o; o.x = v[j]; o.y = v[j + 1]; o.z = v[j + 2]; o.w = v[j + 3];
        *(float4*)&Cf[gbase + j] = o;
      }
    }
    if (OBF == 1 || OBF == 2) {
      const size_t crow = ESCAT ? (size_t)posmap[grow] : grow;
      const size_t cbase = crow * Nn + col0 + cs;
      bf16x8 o0, o1;
      #pragma unroll
      for (int j = 0; j < 8; j++) { o0[j] = (__bf16)v[j]; o1[j] = (__bf16)v[8 + j]; }
      *(bf16x8*)&Cb[cbase] = o0;
      *(bf16x8*)&Cb[cbase + 8] = o1;
    }
  }
  if (STATS) {
    __syncthreads();
    if (tid < 128) {
      const int lr = tid;
      const int hi = lr >> 6, m2 = (lr >> 4) & 3, rl = lr & 15;
      pstats[(row0 + lr) * ntn + bn] = pst4[m2][(hi << 4) | rl];
    }
  }
}

// ---------------- GEMM2 with fused LN+ReLU on the A operand ----------------
// h = relu(LN_512(c1)) @ w2 + b2 (+R). A staged via registers: load c1b bf16,
// apply (v-mu)*inv*g+b, relu, repack bf16 -> LDS. Stats from pstats (4 partials).
template <int RES>
__global__ __launch_bounds__(256, 2)
void k_gemm2(const __bf16* __restrict__ c1b, const __bf16* __restrict__ BT,
             const float* __restrict__ bias, const float* __restrict__ R,
             const float2* __restrict__ pstats, const float* __restrict__ gamma,
             const float* __restrict__ beta, float* __restrict__ Cf, int Nn) {
  constexpr int K = HD2;
  __shared__ __bf16 lsA[4096];
  __shared__ __bf16 lsB[4096];
  __shared__ float sm[32][132];
  __shared__ float sbias[128];
  __shared__ float smu[128], sinv[128];
  __shared__ float sg[512], sb[512];
  const int tid  = threadIdx.x;
  const int lane = tid & 63;
  const int wave = tid >> 6;
  const int ntn  = Nn >> 7;
  const int bm   = (int)blockIdx.x / ntn;
  const int bn   = (int)blockIdx.x % ntn;
  const size_t row0 = (size_t)bm * 128, col0 = (size_t)bn * 128;
  const int wr = (wave >> 1) * 64, wc = (wave & 1) * 64;
  const int ks = lane >> 4, fr = lane & 15;

  // LN row stats + gamma/beta staging
  if (tid < 128) {
    const float4* pp = (const float4*)&pstats[(row0 + tid) * 4];
    const float4 q0 = pp[0], q1 = pp[1];
    const float su = q0.x + q0.z + q1.x + q1.z;
    const float sq = q0.y + q0.w + q1.y + q1.w;
    const float mu = su * (1.f / K);
    const float var = sq * (1.f / K) - mu * mu;
    smu[tid] = mu;
    sinv[tid] = rsqrtf(var + 1e-5f);
  }
  sg[tid] = gamma[tid]; sg[tid + 256] = gamma[tid + 256];
  sb[tid] = beta[tid];  sb[tid + 256] = beta[tid + 256];
  __syncthreads();

  f32x4 acc[4][4] = {};
  const int s1 = tid, s2 = tid + 256;
  const int r1 = s1 & 127, ks1 = s1 >> 7;
  const int r2 = s2 & 127, ks2 = s2 >> 7;

  for (int k0 = 0; k0 < K; k0 += 32) {
    gl_lds16(BT + (col0 + r1) * K + k0 + ks1 * 8, &lsB[s1 * 8]);
    gl_lds16(BT + (col0 + r2) * K + k0 + ks2 * 8, &lsB[s2 * 8]);
    // A: reg-staged with LN transform
    #pragma unroll
    for (int c = 0; c < 2; c++) {
      const int s = c ? s2 : s1;
      const int r = c ? r2 : r1;
      const int kb = k0 + (c ? ks2 : ks1) * 8;
      const bf16x8 av = *(const bf16x8*)&c1b[(row0 + r) * K + kb];
      const float mu = smu[r], iv = sinv[r];
      bf16x8 ov;
      #pragma unroll
      for (int j = 0; j < 8; j++) {
        const float f = ((float)av[j] - mu) * iv * sg[kb + j] + sb[kb + j];
        ov[j] = (__bf16)fmaxf(f, 0.f);
      }
      *(bf16x8*)&lsA[s * 8] = ov;
    }
    __syncthreads();
    bf16x8 af[4], bfr[4];
    #pragma unroll
    for (int m = 0; m < 4; m++) af[m]  = *(const bf16x8*)&lsA[(ks * 128 + wr + m * 16 + fr) * 8];
    #pragma unroll
    for (int n = 0; n < 4; n++) bfr[n] = *(const bf16x8*)&lsB[(ks * 128 + wc + n * 16 + fr) * 8];
    #pragma unroll
    for (int m = 0; m < 4; m++)
      #pragma unroll
      for (int n = 0; n < 4; n++)
        acc[m][n] = __builtin_amdgcn_mfma_f32_16x16x32_bf16(af[m], bfr[n], acc[m][n], 0, 0, 0);
    __syncthreads();
  }

  if (tid < 128) sbias[tid] = bias[col0 + tid];
  const int fq = ks;
  const int rbase = (wave >> 1) * 16 + fq * 4;
  const int rr = tid >> 3, cs = (tid & 7) * 16;
  #pragma unroll
  for (int m = 0; m < 4; m++) {
    if (m) __syncthreads();
    #pragma unroll
    for (int n = 0; n < 4; n++)
      #pragma unroll
      for (int r = 0; r < 4; r++)
        sm[rbase + r][wc + n * 16 + fr] = acc[m][n][r];
    __syncthreads();
    const size_t grow = row0 + ((rr & 16) ? 64 : 0) + m * 16 + (rr & 15);
    const size_t gbase = grow * Nn + col0 + cs;
    float v[16];
    #pragma unroll
    for (int j = 0; j < 16; j++) v[j] = sm[rr][cs + j] + sbias[cs + j];
    if (RES) {
      #pragma unroll
      for (int j = 0; j < 16; j += 4) {
        const float4 rv = *(const float4*)&R[gbase + j];
        v[j] += rv.x; v[j + 1] += rv.y; v[j + 2] += rv.z; v[j + 3] += rv.w;
      }
    }
    #pragma unroll
    for (int j = 0; j < 16; j += 4) {
      float4 o; o.x = v[j]; o.y = v[j + 1]; o.z = v[j + 2]; o.w = v[j + 3];
      *(float4*)&Cf[gbase + j] = o;
    }
  }
}

// ---------------- wave-per-node softmax aggregation ----------------
// e_csr is CSR-position-ordered: sequential reads. z gathered via readlane src.
__global__ __launch_bounds__(256)
void k_msg(const __bf16* __restrict__ zb, const __bf16* __restrict__ ecsr,
           const int* __restrict__ row_start, const int* __restrict__ deg,
           const int2* __restrict__ csr_es, const float* __restrict__ tvec,
           int layer, __bf16* __restrict__ a1) {
  const int wv   = __builtin_amdgcn_readfirstlane(threadIdx.x >> 6);
  const int lane = threadIdx.x & 63;
  const int node = blockIdx.x * 4 + wv;
  const int st = __builtin_amdgcn_readfirstlane(row_start[node]);
  const int dg = __builtin_amdgcn_readfirstlane(deg[node]);
  const float t = tvec[layer];
  const int f0 = lane * 4;

  int my_src = 0;
  if (lane < dg) my_src = csr_es[st + lane].y;

  float den[4] = {0.f, 0.f, 0.f, 0.f}, agg[4] = {0.f, 0.f, 0.f, 0.f};
  const int dmain = dg < 64 ? dg : 64;
  int j = 0;
  for (; j + 4 <= dmain; j += 4) {
    bf16x4 zv[4], ev[4];
    #pragma unroll
    for (int u = 0; u < 4; u++) {
      const int sn = __builtin_amdgcn_readlane(my_src, j + u);
      zv[u] = *(const bf16x4*)&zb[(size_t)sn * HD + f0];
      ev[u] = *(const bf16x4*)&ecsr[(size_t)(st + j + u) * HD + f0];
    }
    #pragma unroll
    for (int u = 0; u < 4; u++)
      #pragma unroll
      for (int q = 0; q < 4; q++) {
        const float m  = fmaxf((float)zv[u][q] + (float)ev[u][q], 0.f) + 1e-7f;
        const float ex = __expf(m * t);
        den[q] += ex;
        agg[q] += m * ex;
      }
  }
  for (; j < dmain; j++) {
    const int sn = __builtin_amdgcn_readlane(my_src, j);
    const bf16x4 zv = *(const bf16x4*)&zb[(size_t)sn * HD + f0];
    const bf16x4 ev = *(const bf16x4*)&ecsr[(size_t)(st + j) * HD + f0];
    #pragma unroll
    for (int q = 0; q < 4; q++) {
      const float m  = fmaxf((float)zv[q] + (float)ev[q], 0.f) + 1e-7f;
      const float ex = __expf(m * t);
      den[q] += ex;
      agg[q] += m * ex;
    }
  }
  for (int jj = 64; jj < dg; jj++) {  // cold path
    const int2 pr = csr_es[st + jj];
    const bf16x4 zv = *(const bf16x4*)&zb[(size_t)pr.y * HD + f0];
    const bf16x4 ev = *(const bf16x4*)&ecsr[(size_t)(st + jj) * HD + f0];
    #pragma unroll
    for (int q = 0; q < 4; q++) {
      const float m  = fmaxf((float)zv[q] + (float)ev[q], 0.f) + 1e-7f;
      const float ex = __expf(m * t);
      den[q] += ex;
      agg[q] += m * ex;
    }
  }
  const bf16x4 sv = *(const bf16x4*)&zb[(size_t)node * HD + f0];
  bf16x4 r;
  #pragma unroll
  for (int q = 0; q < 4; q++) {
    const float res = (dg > 0) ? agg[q] / (den[q] + 1e-16f) : 0.f;
    r[q] = (__bf16)(res + (float)sv[q]);
  }
  *(bf16x4*)&a1[(size_t)node * HD + f0] = r;
}

// ---------------- LN kernels ----------------
// zb = bf16(relu(LN_256(h))). 4 rows/block.
__global__ __launch_bounds__(256)
void k_prenorm(const float* __restrict__ h, const float* __restrict__ g,
               const float* __restrict__ b, __bf16* __restrict__ zb) {
  const int row  = blockIdx.x * 4 + (threadIdx.x >> 6);
  const int lane = threadIdx.x & 63;
  const float4 v = *(const float4*)&h[(size_t)row * HD + lane * 4];
  float s = v.x + v.y + v.z + v.w;
  for (int o = 1; o < 64; o <<= 1) s += __shfl_xor(s, o);
  const float mu = s * (1.f / HD);
  const float dx = v.x - mu, dy = v.y - mu, dz = v.z - mu, dw = v.w - mu;
  float q = dx * dx + dy * dy + dz * dz + dw * dw;
  for (int o = 1; o < 64; o <<= 1) q += __shfl_xor(q, o);
  const float inv = rsqrtf(q * (1.f / HD) + 1e-5f);
  const float4 gv = *(const float4*)&g[lane * 4];
  const float4 bv = *(const float4*)&b[lane * 4];
  bf16x4 r;
  r[0] = (__bf16)fmaxf(dx * inv * gv.x + bv.x, 0.f);
  r[1] = (__bf16)fmaxf(dy * inv * gv.y + bv.y, 0.f);
  r[2] = (__bf16)fmaxf(dz * inv * gv.z + bv.z, 0.f);
  r[3] = (__bf16)fmaxf(dw * inv * gv.w + bv.w, 0.f);
  *(bf16x4*)&zb[(size_t)row * HD + lane * 4] = r;
}

// ---------------- fused final LN + head: out = relu(LN(h)) @ lin_w + lin_b ----------------
__global__ __launch_bounds__(256)
void k_headln(const float* __restrict__ h, const float* __restrict__ g,
              const float* __restrict__ b, const float* __restrict__ lw,
              const float* __restrict__ lb, float* __restrict__ out) {
  __shared__ float slw[256 * 16];   // [k][c]
  __shared__ float srow[16 * 256];
  const int t = threadIdx.x;
  const size_t row0 = (size_t)blockIdx.x * 16;
  #pragma unroll
  for (int j = 0; j < 16; j++) slw[j * 256 + t] = lw[j * 256 + t];
  const int rl = t >> 4, col = t & 15;
  // each thread: 16 contiguous features of row rl
  float v[16];
  float s = 0.f, sq = 0.f;
  #pragma unroll
  for (int j = 0; j < 16; j += 4) {
    const float4 hv = *(const float4*)&h[(row0 + rl) * HD + col * 16 + j];
    v[j] = hv.x; v[j + 1] = hv.y; v[j + 2] = hv.z; v[j + 3] = hv.w;
  }
  #pragma unroll
  for (int j = 0; j < 16; j++) { s += v[j]; sq += v[j] * v[j]; }
  #pragma unroll
  for (int o = 1; o < 16; o <<= 1) { s += __shfl_xor(s, o); sq += __shfl_xor(sq, o); }
  const float mu = s * (1.f / HD);
  const float inv = rsqrtf(sq * (1.f / HD) - mu * mu + 1e-5f);
  #pragma unroll
  for (int j = 0; j < 16; j += 4) {
    const float4 gv = *(const float4*)&g[col * 16 + j];
    const float4 bv = *(const float4*)&b[col * 16 + j];
    srow[rl * 256 + col * 16 + j]     = fmaxf((v[j]     - mu) * inv * gv.x + bv.x, 0.f);
    srow[rl * 256 + col * 16 + j + 1] = fmaxf((v[j + 1] - mu) * inv * gv.y + bv.y, 0.f);
    srow[rl * 256 + col * 16 + j + 2] = fmaxf((v[j + 2] - mu) * inv * gv.z + bv.z, 0.f);
    srow[rl * 256 + col * 16 + j + 3] = fmaxf((v[j + 3] - mu) * inv * gv.w + bv.w, 0.f);
  }
  __syncthreads();
  float acc = lb[col];
  #pragma unroll 8
  for (int k = 0; k < 256; k++) acc += srow[rl * 256 + k] * slw[k * 16 + col];
  out[(row0 + rl) * 16 + col] = acc;
}

// ---------------- host launch ----------------
extern "C" void kernel_launch(void* const* d_in, const int* in_sizes, int n_in,
                              void* d_out, int out_size, void* d_ws, size_t ws_size,
                              hipStream_t stream) {
  const float* x     = (const float*)d_in[0];
  const int*   ei    = (const int*)d_in[1];
  const float* ea    = (const float*)d_in[2];
  const float* enc_w = (const float*)d_in[3];
  const float* enc_b = (const float*)d_in[4];
  const float* ee_w  = (const float*)d_in[5];
  const float* ee_b  = (const float*)d_in[6];
  const float* w1    = (const float*)d_in[7];
  const float* b1    = (const float*)d_in[8];
  const float* lng   = (const float*)d_in[9];
  const float* lnb   = (const float*)d_in[10];
  const float* w2    = (const float*)d_in[11];
  const float* b2    = (const float*)d_in[12];
  const float* tvec  = (const float*)d_in[13];
  const float* ng    = (const float*)d_in[14];
  const float* nb    = (const float*)d_in[15];
  const float* lin_w = (const float*)d_in[16];
  const float* lin_b = (const float*)d_in[17];

  uint8_t* p = (uint8_t*)d_ws;
  auto alloc = [&](size_t bytes) { uint8_t* r = p; p += (bytes + 255) & ~(size_t)255; return r; };
  __bf16* e_csr  = (__bf16*)alloc((size_t)NE * HD * 2);
  float*  h      = (float*) alloc((size_t)NN * HD * 4);
  __bf16* hb     = (__bf16*)alloc((size_t)NN * HD * 2);
  __bf16* zb     = (__bf16*)alloc((size_t)NN * HD * 2);
  __bf16* a1     = (__bf16*)alloc((size_t)NN * HD * 2);
  __bf16* c1b    = (__bf16*)alloc((size_t)NN * HD2 * 2);
  float2* pstats = (float2*)alloc((size_t)NN * 4 * 8);
  __bf16* xbf    = (__bf16*)alloc((size_t)NN * DIN * 2);
  __bf16* eabf   = (__bf16*)alloc((size_t)NE * DE * 2);
  __bf16* enc_wT = (__bf16*)alloc((size_t)HD * DIN * 2);
  __bf16* ee_wT  = (__bf16*)alloc((size_t)HD * DE * 2);
  __bf16* w1T    = (__bf16*)alloc((size_t)4 * HD2 * HD * 2);
  __bf16* w2T    = (__bf16*)alloc((size_t)4 * HD * HD2 * 2);
  int* deg       = (int*)alloc((size_t)NN * 4);
  int* cursor    = (int*)alloc((size_t)NN * 4);   // contiguous with deg -> one memset
  int* row_start = (int*)alloc((size_t)NN * 4);
  int* posmap    = (int*)alloc((size_t)NE * 4);
  int2* csr_es   = (int2*)alloc((size_t)NE * 8);

  const int* srcp = ei;
  const int* dstp = ei + NE;

  hipMemsetAsync(deg, 0, (size_t)NN * 8, stream);  // deg + cursor
  k_hist<<<NE / 256, 256, 0, stream>>>(dstp, deg);
  k_scan<<<1, 1024, 0, stream>>>(deg, row_start);
  k_scatter<<<NE / 256, 256, 0, stream>>>(srcp, dstp, row_start, cursor, csr_es);
  k_sort<<<NN / 256, 256, 0, stream>>>(row_start, deg, csr_es, posmap);

  const int prep_total = DIN * HD + DE * HD + 4 * HD * HD2 + 4 * HD2 * HD +
                         NN * DIN / 4 + NE * DE / 4;
  k_prep<<<(prep_total + 255) / 256, 256, 0, stream>>>(enc_w, ee_w, w1, w2, x, ea,
                                                       enc_wT, ee_wT, w1T, w2T, xbf, eabf);

  // node encoder: h(f32) + hb(bf16)
  k_gemm<0, 2, 0, 0><<<(NN / 128) * (HD / 128), 256, 0, stream>>>(
      xbf, enc_wT, enc_b, nullptr, h, hb, nullptr, nullptr, NN, HD, DIN);
  // edge encoder -> e_csr (CSR-position-ordered rows)
  k_gemm<0, 1, 0, 1><<<(NE / 128) * (HD / 128), 256, 0, stream>>>(
      eabf, ee_wT, ee_b, nullptr, nullptr, e_csr, posmap, nullptr, NE, HD, DE);

  for (int i = 0; i < 4; i++) {
    const __bf16* zin = (i == 0) ? hb : zb;
    k_msg<<<NN / 4, 256, 0, stream>>>(zin, e_csr, row_start, deg, csr_es, tvec, i, a1);
    // GEMM1: c1b = bf16(a1 @ w1 + b1) + per-row stats
    k_gemm<0, 1, 1, 0><<<(NN / 128) * (HD2 / 128), 256, 0, stream>>>(
        a1, w1T + (size_t)i * HD2 * HD, b1 + (size_t)i * HD2, nullptr, nullptr, c1b,
        nullptr, pstats, NN, HD2, HD);
    // GEMM2 (fused LN512+ReLU on A): h = relu(LN(c1)) @ w2 + b2 (+h)
    if (i == 0)
      k_gemm2<0><<<(NN / 128) * (HD / 128), 256, 0, stream>>>(
          c1b, w2T + (size_t)i * HD * HD2, b2 + (size_t)i * HD, nullptr, pstats,
          lng + (size_t)i * HD2, lnb + (size_t)i * HD2, h, HD);
    else
      k_gemm2<1><<<(NN / 128) * (HD / 128), 256, 0, stream>>>(
          c1b, w2T + (size_t)i * HD * HD2, b2 + (size_t)i * HD, h, pstats,
          lng + (size_t)i * HD2, lnb + (size_t)i * HD2, h, HD);
    if (i < 3)
      k_prenorm<<<NN / 4, 256, 0, stream>>>(h, ng + (size_t)(i + 1) * HD,
                                            nb + (size_t)(i + 1) * HD, zb);
  }

  k_headln<<<NN / 16, 256, 0, stream>>>(h, ng, nb, lin_w, lin_b, (float*)d_out);
}

// Round 8
// 407.596 us; speedup vs baseline: 1.1444x; 1.0054x over previous
//
#include <hip/hip_runtime.h>
#include <stdint.h>
#include <math.h>

// DeeperGNN forward on MI355X.
// R8: single-barrier dbuf K-loops (T3-min), T14 A-staging in gemm2, XCD swizzle,
// k_msg 8-deep load groups. Numerics identical to R7.

typedef __bf16 bf16x8 __attribute__((ext_vector_type(8)));
typedef __bf16 bf16x4 __attribute__((ext_vector_type(4)));
typedef float  f32x4  __attribute__((ext_vector_type(4)));

constexpr int NN   = 16384;   // nodes
constexpr int NE   = 131072;  // edges
constexpr int DIN  = 128;
constexpr int DE   = 64;
constexpr int HD   = 256;
constexpr int HD2  = 512;

__device__ __forceinline__ void gl_lds16(const __bf16* g, __bf16* l) {
  __builtin_amdgcn_global_load_lds((const __attribute__((address_space(1))) void*)g,
                                   (__attribute__((address_space(3))) void*)l, 16, 0, 0);
}

// ---------------- CSR build ----------------
__global__ void k_hist(const int* __restrict__ dst, int* __restrict__ deg) {
  int e = blockIdx.x * 256 + threadIdx.x;
  if (e < NE) atomicAdd(&deg[dst[e]], 1);
}

__global__ __launch_bounds__(1024) void k_scan(const int* __restrict__ deg,
                                               int* __restrict__ row_start) {
  __shared__ int part[1024];
  const int t = threadIdx.x;
  const int base = t * 16;
  int loc[16];
  int s = 0;
  #pragma unroll
  for (int i = 0; i < 16; i++) { loc[i] = s; s += deg[base + i]; }
  part[t] = s;
  __syncthreads();
  for (int off = 1; off < 1024; off <<= 1) {
    int v = (t >= off) ? part[t - off] : 0;
    __syncthreads();
    part[t] += v;
    __syncthreads();
  }
  const int excl = (t == 0) ? 0 : part[t - 1];
  #pragma unroll
  for (int i = 0; i < 16; i++) row_start[base + i] = excl + loc[i];
}

__global__ void k_scatter(const int* __restrict__ src, const int* __restrict__ dst,
                          const int* __restrict__ row_start, int* __restrict__ cursor,
                          int2* __restrict__ csr_es) {
  int e = blockIdx.x * 256 + threadIdx.x;
  if (e >= NE) return;
  const int d = dst[e];
  const int p = atomicAdd(&cursor[d], 1);
  csr_es[row_start[d] + p] = make_int2(e, src[e]);
}

// canonical per-node eid-order (determinism) + posmap[eid] = CSR position
__global__ void k_sort(const int* __restrict__ row_start, const int* __restrict__ deg,
                       int2* __restrict__ csr_es, int* __restrict__ posmap) {
  int n = blockIdx.x * 256 + threadIdx.x;
  if (n >= NN) return;
  const int st = row_start[n], dg = deg[n];
  for (int a = 1; a < dg; a++) {
    int2 k = csr_es[st + a];
    int b = a - 1;
    while (b >= 0 && csr_es[st + b].x > k.x) { csr_es[st + b + 1] = csr_es[st + b]; b--; }
    csr_es[st + b + 1] = k;
  }
  for (int a = 0; a < dg; a++) posmap[csr_es[st + a].x] = st + a;
}

// ---------------- merged prep: weight transposes + input bf16 casts ----------------
__global__ void k_prep(const float* __restrict__ enc_w, const float* __restrict__ ee_w,
                       const float* __restrict__ w1, const float* __restrict__ w2,
                       const float* __restrict__ x, const float* __restrict__ ea,
                       __bf16* __restrict__ enc_wT, __bf16* __restrict__ ee_wT,
                       __bf16* __restrict__ w1T, __bf16* __restrict__ w2T,
                       __bf16* __restrict__ xbf, __bf16* __restrict__ eabf) {
  int i = blockIdx.x * 256 + threadIdx.x;
  const int S0 = DIN * HD, S1 = DE * HD, S2 = 4 * HD * HD2, S3 = 4 * HD2 * HD;
  const int S4 = NN * DIN / 4, S5 = NE * DE / 4;
  if (i < S0) { int k = i / HD, n = i % HD; enc_wT[n * DIN + k] = (__bf16)enc_w[i]; return; }
  i -= S0;
  if (i < S1) { int k = i / HD, n = i % HD; ee_wT[n * DE + k] = (__bf16)ee_w[i]; return; }
  i -= S1;
  if (i < S2) {
    int l = i / (HD * HD2), r = i % (HD * HD2), k = r / HD2, n = r % HD2;
    w1T[(size_t)l * HD * HD2 + (size_t)n * HD + k] = (__bf16)w1[i]; return;
  }
  i -= S2;
  if (i < S3) {
    int l = i / (HD2 * HD), r = i % (HD2 * HD), k = r / HD, n = r % HD;
    w2T[(size_t)l * HD2 * HD + (size_t)n * HD2 + k] = (__bf16)w2[i]; return;
  }
  i -= S3;
  if (i < S4) {
    float4 v = ((const float4*)x)[i];
    bf16x4 r; r[0] = (__bf16)v.x; r[1] = (__bf16)v.y; r[2] = (__bf16)v.z; r[3] = (__bf16)v.w;
    ((bf16x4*)xbf)[i] = r; return;
  }
  i -= S4;
  if (i < S5) {
    float4 v = ((const float4*)ea)[i];
    bf16x4 r; r[0] = (__bf16)v.x; r[1] = (__bf16)v.y; r[2] = (__bf16)v.z; r[3] = (__bf16)v.w;
    ((bf16x4*)eabf)[i] = r; return;
  }
}

// ---------------- MFMA GEMM, 128x128 tile, dbuf 1-barrier K-loop ----------------
// OBF: 0=f32 Cf, 1=bf16 Cb, 2=dual. STATS: per-row (sum,sumsq) partials.
// ESCAT: Cb rows remapped through posmap. XCD swizzle: bn-siblings share XCD L2.
template <int RES, int OBF, int STATS, int ESCAT>
__global__ __launch_bounds__(256, 2)
void k_gemm(const __bf16* __restrict__ A, const __bf16* __restrict__ BT,
            const float* __restrict__ bias, const float* __restrict__ R,
            float* __restrict__ Cf, __bf16* __restrict__ Cb,
            const int* __restrict__ posmap, float2* __restrict__ pstats,
            int M, int Nn, int K) {
  __shared__ __bf16 lsA[2][4096];
  __shared__ __bf16 lsB[2][4096];
  __shared__ float sm[32][132];
  __shared__ float sbias[128];
  __shared__ float2 pst4[4][32];
  const int tid  = threadIdx.x;
  const int lane = tid & 63;
  const int wave = tid >> 6;
  const int ntn  = Nn >> 7;
  const int bid  = (int)blockIdx.x;
  const int bn   = (bid >> 3) % ntn;                 // XCD swizzle: same-bm -> same XCD
  const int bm   = (bid & 7) + ((bid >> 3) / ntn) * 8;
  const size_t row0 = (size_t)bm * 128, col0 = (size_t)bn * 128;
  const int wr = (wave >> 1) * 64, wc = (wave & 1) * 64;
  const int ks = lane >> 4, fr = lane & 15;

  f32x4 acc[4][4] = {};

  const int s1 = tid, s2 = tid + 256;
  const int r1 = s1 & 127, ks1 = s1 >> 7;
  const int r2 = s2 & 127, ks2 = s2 >> 7;

  auto stage = [&](int buf, int k0) {
    gl_lds16(A  + (row0 + r1) * K + k0 + ks1 * 8, &lsA[buf][s1 * 8]);
    gl_lds16(A  + (row0 + r2) * K + k0 + ks2 * 8, &lsA[buf][s2 * 8]);
    gl_lds16(BT + (col0 + r1) * K + k0 + ks1 * 8, &lsB[buf][s1 * 8]);
    gl_lds16(BT + (col0 + r2) * K + k0 + ks2 * 8, &lsB[buf][s2 * 8]);
  };

  const int nk = K / 32;
  stage(0, 0);
  __syncthreads();
  int cur = 0;
  for (int t = 0; t < nk; t++) {
    if (t + 1 < nk) stage(cur ^ 1, (t + 1) * 32);   // issue next tile first
    bf16x8 af[4], bfr[4];
    #pragma unroll
    for (int m = 0; m < 4; m++) af[m]  = *(const bf16x8*)&lsA[cur][(ks * 128 + wr + m * 16 + fr) * 8];
    #pragma unroll
    for (int n = 0; n < 4; n++) bfr[n] = *(const bf16x8*)&lsB[cur][(ks * 128 + wc + n * 16 + fr) * 8];
    #pragma unroll
    for (int m = 0; m < 4; m++)
      #pragma unroll
      for (int n = 0; n < 4; n++)
        acc[m][n] = __builtin_amdgcn_mfma_f32_16x16x32_bf16(af[m], bfr[n], acc[m][n], 0, 0, 0);
    __syncthreads();          // next buffer ready + cur safe to overwrite
    cur ^= 1;
  }

  // ---- coalesced epilogue (LDS-transposed) ----
  if (tid < 128) sbias[tid] = bias[col0 + tid];
  const int fq = ks;
  const int rbase = (wave >> 1) * 16 + fq * 4;
  const int rr = tid >> 3, cs = (tid & 7) * 16;
  #pragma unroll
  for (int m = 0; m < 4; m++) {
    if (m) __syncthreads();
    #pragma unroll
    for (int n = 0; n < 4; n++)
      #pragma unroll
      for (int r = 0; r < 4; r++)
        sm[rbase + r][wc + n * 16 + fr] = acc[m][n][r];
    __syncthreads();
    const size_t lrow = ((rr & 16) ? 64 : 0) + m * 16 + (rr & 15);
    const size_t grow = row0 + lrow;
    float v[16];
    #pragma unroll
    for (int j = 0; j < 16; j++) v[j] = sm[rr][cs + j] + sbias[cs + j];
    if (STATS) {
      float ssum = 0.f, ssq = 0.f;
      #pragma unroll
      for (int j = 0; j < 16; j++) { ssum += v[j]; ssq += v[j] * v[j]; }
      #pragma unroll
      for (int o = 1; o < 8; o <<= 1) {
        ssum += __shfl_xor(ssum, o);
        ssq  += __shfl_xor(ssq, o);
      }
      if ((tid & 7) == 0) pst4[m][rr].x = ssum, pst4[m][rr].y = ssq;
    }
    const size_t gbase = grow * Nn + col0 + cs;
    if (RES) {
      #pragma unroll
      for (int j = 0; j < 16; j += 4) {
        const float4 rv = *(const float4*)&R[gbase + j];
        v[j] += rv.x; v[j + 1] += rv.y; v[j + 2] += rv.z; v[j + 3] += rv.w;
      }
    }
    if (OBF == 0 || OBF == 2) {
      #pragma unroll
      for (int j = 0; j < 16; j += 4) {
        float4 o; o.x = v[j]; o.y = v[j + 1]; o.z = v[j + 2]; o.w = v[j + 3];
        *(float4*)&Cf[gbase + j] = o;
      }
    }
    if (OBF == 1 || OBF == 2) {
      const size_t crow = ESCAT ? (size_t)posmap[grow] : grow;
      const size_t cbase = crow * Nn + col0 + cs;
      bf16x8 o0, o1;
      #pragma unroll
      for (int j = 0; j < 8; j++) { o0[j] = (__bf16)v[j]; o1[j] = (__bf16)v[8 + j]; }
      *(bf16x8*)&Cb[cbase] = o0;
      *(bf16x8*)&Cb[cbase + 8] = o1;
    }
  }
  if (STATS) {
    __syncthreads();
    if (tid < 128) {
      const int lr = tid;
      const int hi = lr >> 6, m2 = (lr >> 4) & 3, rl = lr & 15;
      pstats[(row0 + lr) * ntn + bn] = pst4[m2][(hi << 4) | rl];
    }
  }
}

// ---------------- GEMM2: h = relu(LN_512(c1)) @ w2 + b2 (+R), T14 A-staging ----
template <int RES>
__global__ __launch_bounds__(256, 2)
void k_gemm2(const __bf16* __restrict__ c1b, const __bf16* __restrict__ BT,
             const float* __restrict__ bias, const float* __restrict__ R,
             const float2* __restrict__ pstats, const float* __restrict__ gamma,
             const float* __restrict__ beta, float* __restrict__ Cf, int Nn) {
  constexpr int K = HD2;
  __shared__ __bf16 lsA[2][4096];
  __shared__ __bf16 lsB[2][4096];
  __shared__ float sm[32][132];
  __shared__ float sbias[128];
  __shared__ float smu[128], sinv[128];
  __shared__ float sg[512], sb[512];
  const int tid  = threadIdx.x;
  const int lane = tid & 63;
  const int wave = tid >> 6;
  const int ntn  = Nn >> 7;
  const int bid  = (int)blockIdx.x;
  const int bn   = (bid >> 3) % ntn;
  const int bm   = (bid & 7) + ((bid >> 3) / ntn) * 8;
  const size_t row0 = (size_t)bm * 128, col0 = (size_t)bn * 128;
  const int wr = (wave >> 1) * 64, wc = (wave & 1) * 64;
  const int ks = lane >> 4, fr = lane & 15;

  if (tid < 128) {
    const float4* pp = (const float4*)&pstats[(row0 + tid) * 4];
    const float4 q0 = pp[0], q1 = pp[1];
    const float su = q0.x + q0.z + q1.x + q1.z;
    const float sq = q0.y + q0.w + q1.y + q1.w;
    const float mu = su * (1.f / K);
    const float var = sq * (1.f / K) - mu * mu;
    smu[tid] = mu;
    sinv[tid] = rsqrtf(var + 1e-5f);
  }
  sg[tid] = gamma[tid]; sg[tid + 256] = gamma[tid + 256];
  sb[tid] = beta[tid];  sb[tid + 256] = beta[tid + 256];
  __syncthreads();

  const int s1 = tid, s2 = tid + 256;
  const int r1 = s1 & 127, ks1 = s1 >> 7;
  const int r2 = s2 & 127, ks2 = s2 >> 7;
  const float mu1 = smu[r1], iv1 = sinv[r1];   // r2 == r1 (chunk2 differs only in ks)
  f32x4 acc[4][4] = {};

  auto stageB = [&](int buf, int k0) {
    gl_lds16(BT + (col0 + r1) * K + k0 + ks1 * 8, &lsB[buf][s1 * 8]);
    gl_lds16(BT + (col0 + r2) * K + k0 + ks2 * 8, &lsB[buf][s2 * 8]);
  };
  auto loadA = [&](int k0, bf16x8& a0, bf16x8& a1v) {
    a0  = *(const bf16x8*)&c1b[(row0 + r1) * K + k0 + ks1 * 8];
    a1v = *(const bf16x8*)&c1b[(row0 + r2) * K + k0 + ks2 * 8];
  };
  auto writeA = [&](int buf, int k0, const bf16x8& a0, const bf16x8& a1v) {
    const int kb1 = k0 + ks1 * 8, kb2 = k0 + ks2 * 8;
    bf16x8 o0, o1;
    #pragma unroll
    for (int j = 0; j < 8; j++) {
      const float f0 = ((float)a0[j]  - mu1) * iv1 * sg[kb1 + j] + sb[kb1 + j];
      const float f1 = ((float)a1v[j] - mu1) * iv1 * sg[kb2 + j] + sb[kb2 + j];
      o0[j] = (__bf16)fmaxf(f0, 0.f);
      o1[j] = (__bf16)fmaxf(f1, 0.f);
    }
    *(bf16x8*)&lsA[buf][s1 * 8] = o0;
    *(bf16x8*)&lsA[buf][s2 * 8] = o1;
  };

  const int nk = K / 32;
  {
    bf16x8 a0, a1v;
    loadA(0, a0, a1v);
    stageB(0, 0);
    writeA(0, 0, a0, a1v);
  }
  __syncthreads();
  int cur = 0;
  for (int t = 0; t < nk; t++) {
    bf16x8 a0, a1v;
    const bool more = (t + 1 < nk);
    if (more) {
      stageB(cur ^ 1, (t + 1) * 32);   // issue B loads
      loadA((t + 1) * 32, a0, a1v);    // issue A loads (completes under MFMA below)
    }
    bf16x8 af[4], bfr[4];
    #pragma unroll
    for (int m = 0; m < 4; m++) af[m]  = *(const bf16x8*)&lsA[cur][(ks * 128 + wr + m * 16 + fr) * 8];
    #pragma unroll
    for (int n = 0; n < 4; n++) bfr[n] = *(const bf16x8*)&lsB[cur][(ks * 128 + wc + n * 16 + fr) * 8];
    #pragma unroll
    for (int m = 0; m < 4; m++)
      #pragma unroll
      for (int n = 0; n < 4; n++)
        acc[m][n] = __builtin_amdgcn_mfma_f32_16x16x32_bf16(af[m], bfr[n], acc[m][n], 0, 0, 0);
    if (more) writeA(cur ^ 1, (t + 1) * 32, a0, a1v);   // transform+ds_write late (T14)
    __syncthreads();
    cur ^= 1;
  }

  if (tid < 128) sbias[tid] = bias[col0 + tid];
  const int fq = ks;
  const int rbase = (wave >> 1) * 16 + fq * 4;
  const int rr = tid >> 3, cs = (tid & 7) * 16;
  #pragma unroll
  for (int m = 0; m < 4; m++) {
    if (m) __syncthreads();
    #pragma unroll
    for (int n = 0; n < 4; n++)
      #pragma unroll
      for (int r = 0; r < 4; r++)
        sm[rbase + r][wc + n * 16 + fr] = acc[m][n][r];
    __syncthreads();
    const size_t grow = row0 + ((rr & 16) ? 64 : 0) + m * 16 + (rr & 15);
    const size_t gbase = grow * Nn + col0 + cs;
    float v[16];
    #pragma unroll
    for (int j = 0; j < 16; j++) v[j] = sm[rr][cs + j] + sbias[cs + j];
    if (RES) {
      #pragma unroll
      for (int j = 0; j < 16; j += 4) {
        const float4 rv = *(const float4*)&R[gbase + j];
        v[j] += rv.x; v[j + 1] += rv.y; v[j + 2] += rv.z; v[j + 3] += rv.w;
      }
    }
    #pragma unroll
    for (int j = 0; j < 16; j += 4) {
      float4 o; o.x = v[j]; o.y = v[j + 1]; o.z = v[j + 2]; o.w = v[j + 3];
      *(float4*)&Cf[gbase + j] = o;
    }
  }
}

// ---------------- wave-per-node softmax aggregation (8-deep groups) ----------------
__global__ __launch_bounds__(256)
void k_msg(const __bf16* __restrict__ zb, const __bf16* __restrict__ ecsr,
           const int* __restrict__ row_start, const int* __restrict__ deg,
           const int2* __restrict__ csr_es, const float* __restrict__ tvec,
           int layer, __bf16* __restrict__ a1) {
  const int wv   = __builtin_amdgcn_readfirstlane(threadIdx.x >> 6);
  const int lane = threadIdx.x & 63;
  const int node = blockIdx.x * 4 + wv;
  const int st = __builtin_amdgcn_readfirstlane(row_start[node]);
  const int dg = __builtin_amdgcn_readfirstlane(deg[node]);
  const float t = tvec[layer];
  const int f0 = lane * 4;

  int my_src = 0;
  if (lane < dg) my_src = csr_es[st + lane].y;
  const bf16x4 sv = *(const bf16x4*)&zb[(size_t)node * HD + f0];

  float den[4] = {0.f, 0.f, 0.f, 0.f}, agg[4] = {0.f, 0.f, 0.f, 0.f};
  const int dmain = dg < 64 ? dg : 64;
  int j = 0;
  for (; j + 8 <= dmain; j += 8) {
    bf16x4 zv[8], ev[8];
    #pragma unroll
    for (int u = 0; u < 8; u++) {
      const int sn = __builtin_amdgcn_readlane(my_src, j + u);
      zv[u] = *(const bf16x4*)&zb[(size_t)sn * HD + f0];
      ev[u] = *(const bf16x4*)&ecsr[(size_t)(st + j + u) * HD + f0];
    }
    #pragma unroll
    for (int u = 0; u < 8; u++)
      #pragma unroll
      for (int q = 0; q < 4; q++) {
        const float m  = fmaxf((float)zv[u][q] + (float)ev[u][q], 0.f) + 1e-7f;
        const float ex = __expf(m * t);
        den[q] += ex;
        agg[q] += m * ex;
      }
  }
  for (; j + 4 <= dmain; j += 4) {
    bf16x4 zv[4], ev[4];
    #pragma unroll
    for (int u = 0; u < 4; u++) {
      const int sn = __builtin_amdgcn_readlane(my_src, j + u);
      zv[u] = *(const bf16x4*)&zb[(size_t)sn * HD + f0];
      ev[u] = *(const bf16x4*)&ecsr[(size_t)(st + j + u) * HD + f0];
    }
    #pragma unroll
    for (int u = 0; u < 4; u++)
      #pragma unroll
      for (int q = 0; q < 4; q++) {
        const float m  = fmaxf((float)zv[u][q] + (float)ev[u][q], 0.f) + 1e-7f;
        const float ex = __expf(m * t);
        den[q] += ex;
        agg[q] += m * ex;
      }
  }
  for (; j < dmain; j++) {
    const int sn = __builtin_amdgcn_readlane(my_src, j);
    const bf16x4 zv = *(const bf16x4*)&zb[(size_t)sn * HD + f0];
    const bf16x4 ev = *(const bf16x4*)&ecsr[(size_t)(st + j) * HD + f0];
    #pragma unroll
    for (int q = 0; q < 4; q++) {
      const float m  = fmaxf((float)zv[q] + (float)ev[q], 0.f) + 1e-7f;
      const float ex = __expf(m * t);
      den[q] += ex;
      agg[q] += m * ex;
    }
  }
  for (int jj = 64; jj < dg; jj++) {  // cold path
    const int2 pr = csr_es[st + jj];
    const bf16x4 zv = *(const bf16x4*)&zb[(size_t)pr.y * HD + f0];
    const bf16x4 ev = *(const bf16x4*)&ecsr[(size_t)(st + jj) * HD + f0];
    #pragma unroll
    for (int q = 0; q < 4; q++) {
      const float m  = fmaxf((float)zv[q] + (float)ev[q], 0.f) + 1e-7f;
      const float ex = __expf(m * t);
      den[q] += ex;
      agg[q] += m * ex;
    }
  }
  bf16x4 r;
  #pragma unroll
  for (int q = 0; q < 4; q++) {
    const float res = (dg > 0) ? agg[q] / (den[q] + 1e-16f) : 0.f;
    r[q] = (__bf16)(res + (float)sv[q]);
  }
  *(bf16x4*)&a1[(size_t)node * HD + f0] = r;
}

// ---------------- LN: zb = bf16(relu(LN_256(h))) ----------------
__global__ __launch_bounds__(256)
void k_prenorm(const float* __restrict__ h, const float* __restrict__ g,
               const float* __restrict__ b, __bf16* __restrict__ zb) {
  const int row  = blockIdx.x * 4 + (threadIdx.x >> 6);
  const int lane = threadIdx.x & 63;
  const float4 v = *(const float4*)&h[(size_t)row * HD + lane * 4];
  float s = v.x + v.y + v.z + v.w;
  for (int o = 1; o < 64; o <<= 1) s += __shfl_xor(s, o);
  const float mu = s * (1.f / HD);
  const float dx = v.x - mu, dy = v.y - mu, dz = v.z - mu, dw = v.w - mu;
  float q = dx * dx + dy * dy + dz * dz + dw * dw;
  for (int o = 1; o < 64; o <<= 1) q += __shfl_xor(q, o);
  const float inv = rsqrtf(q * (1.f / HD) + 1e-5f);
  const float4 gv = *(const float4*)&g[lane * 4];
  const float4 bv = *(const float4*)&b[lane * 4];
  bf16x4 r;
  r[0] = (__bf16)fmaxf(dx * inv * gv.x + bv.x, 0.f);
  r[1] = (__bf16)fmaxf(dy * inv * gv.y + bv.y, 0.f);
  r[2] = (__bf16)fmaxf(dz * inv * gv.z + bv.z, 0.f);
  r[3] = (__bf16)fmaxf(dw * inv * gv.w + bv.w, 0.f);
  *(bf16x4*)&zb[(size_t)row * HD + lane * 4] = r;
}

// ---------------- fused final LN + head ----------------
__global__ __launch_bounds__(256)
void k_headln(const float* __restrict__ h, const float* __restrict__ g,
              const float* __restrict__ b, const float* __restrict__ lw,
              const float* __restrict__ lb, float* __restrict__ out) {
  __shared__ float slw[256 * 16];   // [k][c]
  __shared__ float srow[16 * 256];
  const int t = threadIdx.x;
  const size_t row0 = (size_t)blockIdx.x * 16;
  #pragma unroll
  for (int j = 0; j < 16; j++) slw[j * 256 + t] = lw[j * 256 + t];
  const int rl = t >> 4, col = t & 15;
  float v[16];
  float s = 0.f, sq = 0.f;
  #pragma unroll
  for (int j = 0; j < 16; j += 4) {
    const float4 hv = *(const float4*)&h[(row0 + rl) * HD + col * 16 + j];
    v[j] = hv.x; v[j + 1] = hv.y; v[j + 2] = hv.z; v[j + 3] = hv.w;
  }
  #pragma unroll
  for (int j = 0; j < 16; j++) { s += v[j]; sq += v[j] * v[j]; }
  #pragma unroll
  for (int o = 1; o < 16; o <<= 1) { s += __shfl_xor(s, o); sq += __shfl_xor(sq, o); }
  const float mu = s * (1.f / HD);
  const float inv = rsqrtf(sq * (1.f / HD) - mu * mu + 1e-5f);
  #pragma unroll
  for (int j = 0; j < 16; j += 4) {
    const float4 gv = *(const float4*)&g[col * 16 + j];
    const float4 bv = *(const float4*)&b[col * 16 + j];
    srow[rl * 256 + col * 16 + j]     = fmaxf((v[j]     - mu) * inv * gv.x + bv.x, 0.f);
    srow[rl * 256 + col * 16 + j + 1] = fmaxf((v[j + 1] - mu) * inv * gv.y + bv.y, 0.f);
    srow[rl * 256 + col * 16 + j + 2] = fmaxf((v[j + 2] - mu) * inv * gv.z + bv.z, 0.f);
    srow[rl * 256 + col * 16 + j + 3] = fmaxf((v[j + 3] - mu) * inv * gv.w + bv.w, 0.f);
  }
  __syncthreads();
  float acc = lb[col];
  #pragma unroll 8
  for (int k = 0; k < 256; k++) acc += srow[rl * 256 + k] * slw[k * 16 + col];
  out[(row0 + rl) * 16 + col] = acc;
}

// ---------------- host launch ----------------
extern "C" void kernel_launch(void* const* d_in, const int* in_sizes, int n_in,
                              void* d_out, int out_size, void* d_ws, size_t ws_size,
                              hipStream_t stream) {
  const float* x     = (const float*)d_in[0];
  const int*   ei    = (const int*)d_in[1];
  const float* ea    = (const float*)d_in[2];
  const float* enc_w = (const float*)d_in[3];
  const float* enc_b = (const float*)d_in[4];
  const float* ee_w  = (const float*)d_in[5];
  const float* ee_b  = (const float*)d_in[6];
  const float* w1    = (const float*)d_in[7];
  const float* b1    = (const float*)d_in[8];
  const float* lng   = (const float*)d_in[9];
  const float* lnb   = (const float*)d_in[10];
  const float* w2    = (const float*)d_in[11];
  const float* b2    = (const float*)d_in[12];
  const float* tvec  = (const float*)d_in[13];
  const float* ng    = (const float*)d_in[14];
  const float* nb    = (const float*)d_in[15];
  const float* lin_w = (const float*)d_in[16];
  const float* lin_b = (const float*)d_in[17];

  uint8_t* p = (uint8_t*)d_ws;
  auto alloc = [&](size_t bytes) { uint8_t* r = p; p += (bytes + 255) & ~(size_t)255; return r; };
  __bf16* e_csr  = (__bf16*)alloc((size_t)NE * HD * 2);
  float*  h      = (float*) alloc((size_t)NN * HD * 4);
  __bf16* hb     = (__bf16*)alloc((size_t)NN * HD * 2);
  __bf16* zb     = (__bf16*)alloc((size_t)NN * HD * 2);
  __bf16* a1     = (__bf16*)alloc((size_t)NN * HD * 2);
  __bf16* c1b    = (__bf16*)alloc((size_t)NN * HD2 * 2);
  float2* pstats = (float2*)alloc((size_t)NN * 4 * 8);
  __bf16* xbf    = (__bf16*)alloc((size_t)NN * DIN * 2);
  __bf16* eabf   = (__bf16*)alloc((size_t)NE * DE * 2);
  __bf16* enc_wT = (__bf16*)alloc((size_t)HD * DIN * 2);
  __bf16* ee_wT  = (__bf16*)alloc((size_t)HD * DE * 2);
  __bf16* w1T    = (__bf16*)alloc((size_t)4 * HD2 * HD * 2);
  __bf16* w2T    = (__bf16*)alloc((size_t)4 * HD * HD2 * 2);
  int* deg       = (int*)alloc((size_t)NN * 4);
  int* cursor    = (int*)alloc((size_t)NN * 4);   // contiguous with deg -> one memset
  int* row_start = (int*)alloc((size_t)NN * 4);
  int* posmap    = (int*)alloc((size_t)NE * 4);
  int2* csr_es   = (int2*)alloc((size_t)NE * 8);

  const int* srcp = ei;
  const int* dstp = ei + NE;

  hipMemsetAsync(deg, 0, (size_t)NN * 8, stream);  // deg + cursor
  k_hist<<<NE / 256, 256, 0, stream>>>(dstp, deg);
  k_scan<<<1, 1024, 0, stream>>>(deg, row_start);
  k_scatter<<<NE / 256, 256, 0, stream>>>(srcp, dstp, row_start, cursor, csr_es);
  k_sort<<<NN / 256, 256, 0, stream>>>(row_start, deg, csr_es, posmap);

  const int prep_total = DIN * HD + DE * HD + 4 * HD * HD2 + 4 * HD2 * HD +
                         NN * DIN / 4 + NE * DE / 4;
  k_prep<<<(prep_total + 255) / 256, 256, 0, stream>>>(enc_w, ee_w, w1, w2, x, ea,
                                                       enc_wT, ee_wT, w1T, w2T, xbf, eabf);

  // node encoder: h(f32) + hb(bf16)
  k_gemm<0, 2, 0, 0><<<(NN / 128) * (HD / 128), 256, 0, stream>>>(
      xbf, enc_wT, enc_b, nullptr, h, hb, nullptr, nullptr, NN, HD, DIN);
  // edge encoder -> e_csr (CSR-position-ordered rows)
  k_gemm<0, 1, 0, 1><<<(NE / 128) * (HD / 128), 256, 0, stream>>>(
      eabf, ee_wT, ee_b, nullptr, nullptr, e_csr, posmap, nullptr, NE, HD, DE);

  for (int i = 0; i < 4; i++) {
    const __bf16* zin = (i == 0) ? hb : zb;
    k_msg<<<NN / 4, 256, 0, stream>>>(zin, e_csr, row_start, deg, csr_es, tvec, i, a1);
    // GEMM1: c1b = bf16(a1 @ w1 + b1) + per-row stats
    k_gemm<0, 1, 1, 0><<<(NN / 128) * (HD2 / 128), 256, 0, stream>>>(
        a1, w1T + (size_t)i * HD2 * HD, b1 + (size_t)i * HD2, nullptr, nullptr, c1b,
        nullptr, pstats, NN, HD2, HD);
    // GEMM2 (fused LN512+ReLU on A): h = relu(LN(c1)) @ w2 + b2 (+h)
    if (i == 0)
      k_gemm2<0><<<(NN / 128) * (HD / 128), 256, 0, stream>>>(
          c1b, w2T + (size_t)i * HD * HD2, b2 + (size_t)i * HD, nullptr, pstats,
          lng + (size_t)i * HD2, lnb + (size_t)i * HD2, h, HD);
    else
      k_gemm2<1><<<(NN / 128) * (HD / 128), 256, 0, stream>>>(
          c1b, w2T + (size_t)i * HD * HD2, b2 + (size_t)i * HD, h, pstats,
          lng + (size_t)i * HD2, lnb + (size_t)i * HD2, h, HD);
    if (i < 3)
      k_prenorm<<<NN / 4, 256, 0, stream>>>(h, ng + (size_t)(i + 1) * HD,
                                            nb + (size_t)(i + 1) * HD, zb);
  }

  k_headln<<<NN / 16, 256, 0, stream>>>(h, ng, nb, lin_w, lin_b, (float*)d_out);
}

// Round 9
// 379.959 us; speedup vs baseline: 1.2277x; 1.0727x over previous
//
#include <hip/hip_runtime.h>
#include <stdint.h>
#include <math.h>

// DeeperGNN forward on MI355X.
// R9: wave-parallel rank sort (k_sort was 40us serial-latency-bound, top dispatch).
// Rest = R8: dbuf 1-barrier GEMMs, T14 A-staging gemm2, XCD swizzle, CSR-ordered e.

typedef __bf16 bf16x8 __attribute__((ext_vector_type(8)));
typedef __bf16 bf16x4 __attribute__((ext_vector_type(4)));
typedef float  f32x4  __attribute__((ext_vector_type(4)));

constexpr int NN   = 16384;   // nodes
constexpr int NE   = 131072;  // edges
constexpr int DIN  = 128;
constexpr int DE   = 64;
constexpr int HD   = 256;
constexpr int HD2  = 512;

__device__ __forceinline__ void gl_lds16(const __bf16* g, __bf16* l) {
  __builtin_amdgcn_global_load_lds((const __attribute__((address_space(1))) void*)g,
                                   (__attribute__((address_space(3))) void*)l, 16, 0, 0);
}

// ---------------- CSR build ----------------
__global__ void k_hist(const int* __restrict__ dst, int* __restrict__ deg) {
  int e = blockIdx.x * 256 + threadIdx.x;
  if (e < NE) atomicAdd(&deg[dst[e]], 1);
}

__global__ __launch_bounds__(1024) void k_scan(const int* __restrict__ deg,
                                               int* __restrict__ row_start) {
  __shared__ int part[1024];
  const int t = threadIdx.x;
  const int base = t * 16;
  int loc[16];
  int s = 0;
  #pragma unroll
  for (int i = 0; i < 16; i++) { loc[i] = s; s += deg[base + i]; }
  part[t] = s;
  __syncthreads();
  for (int off = 1; off < 1024; off <<= 1) {
    int v = (t >= off) ? part[t - off] : 0;
    __syncthreads();
    part[t] += v;
    __syncthreads();
  }
  const int excl = (t == 0) ? 0 : part[t - 1];
  #pragma unroll
  for (int i = 0; i < 16; i++) row_start[base + i] = excl + loc[i];
}

__global__ void k_scatter(const int* __restrict__ src, const int* __restrict__ dst,
                          const int* __restrict__ row_start, int* __restrict__ cursor,
                          int2* __restrict__ csr_es) {
  int e = blockIdx.x * 256 + threadIdx.x;
  if (e >= NE) return;
  const int d = dst[e];
  const int p = atomicAdd(&cursor[d], 1);
  csr_es[row_start[d] + p] = make_int2(e, src[e]);
}

// wave-parallel canonical sort: one wave per node; lane's rank = #(smaller eids).
// Deterministic FP order for k_msg; posmap[eid] = final CSR position.
__global__ __launch_bounds__(256)
void k_sortw(const int* __restrict__ row_start, const int* __restrict__ deg,
             int2* __restrict__ csr_es, int* __restrict__ posmap) {
  const int wv   = threadIdx.x >> 6;
  const int lane = threadIdx.x & 63;
  const int node = blockIdx.x * 4 + wv;
  if (node >= NN) return;
  const int st = __builtin_amdgcn_readfirstlane(row_start[node]);
  const int dg = __builtin_amdgcn_readfirstlane(deg[node]);
  if (dg <= 1) {
    if (dg == 1 && lane == 0) posmap[csr_es[st].x] = st;
    return;
  }
  if (dg <= 64) {
    int2 pr = make_int2(0x7fffffff, 0);
    if (lane < dg) pr = csr_es[st + lane];
    int rank = 0;
    for (int j = 0; j < dg; j++) {
      const int ej = __builtin_amdgcn_readlane(pr.x, j);
      if (lane < dg && ej < pr.x) rank++;
    }
    if (lane < dg) {
      csr_es[st + rank] = pr;
      posmap[pr.x] = st + rank;
    }
  } else if (lane == 0) {  // cold fallback, effectively never for Poisson(8)
    for (int a = 1; a < dg; a++) {
      int2 k = csr_es[st + a];
      int b = a - 1;
      while (b >= 0 && csr_es[st + b].x > k.x) { csr_es[st + b + 1] = csr_es[st + b]; b--; }
      csr_es[st + b + 1] = k;
    }
    for (int a = 0; a < dg; a++) posmap[csr_es[st + a].x] = st + a;
  }
}

// ---------------- merged prep: weight transposes + input bf16 casts ----------------
__global__ void k_prep(const float* __restrict__ enc_w, const float* __restrict__ ee_w,
                       const float* __restrict__ w1, const float* __restrict__ w2,
                       const float* __restrict__ x, const float* __restrict__ ea,
                       __bf16* __restrict__ enc_wT, __bf16* __restrict__ ee_wT,
                       __bf16* __restrict__ w1T, __bf16* __restrict__ w2T,
                       __bf16* __restrict__ xbf, __bf16* __restrict__ eabf) {
  int i = blockIdx.x * 256 + threadIdx.x;
  const int S0 = DIN * HD, S1 = DE * HD, S2 = 4 * HD * HD2, S3 = 4 * HD2 * HD;
  const int S4 = NN * DIN / 4, S5 = NE * DE / 4;
  if (i < S0) { int k = i / HD, n = i % HD; enc_wT[n * DIN + k] = (__bf16)enc_w[i]; return; }
  i -= S0;
  if (i < S1) { int k = i / HD, n = i % HD; ee_wT[n * DE + k] = (__bf16)ee_w[i]; return; }
  i -= S1;
  if (i < S2) {
    int l = i / (HD * HD2), r = i % (HD * HD2), k = r / HD2, n = r % HD2;
    w1T[(size_t)l * HD * HD2 + (size_t)n * HD + k] = (__bf16)w1[i]; return;
  }
  i -= S2;
  if (i < S3) {
    int l = i / (HD2 * HD), r = i % (HD2 * HD), k = r / HD, n = r % HD;
    w2T[(size_t)l * HD2 * HD + (size_t)n * HD2 + k] = (__bf16)w2[i]; return;
  }
  i -= S3;
  if (i < S4) {
    float4 v = ((const float4*)x)[i];
    bf16x4 r; r[0] = (__bf16)v.x; r[1] = (__bf16)v.y; r[2] = (__bf16)v.z; r[3] = (__bf16)v.w;
    ((bf16x4*)xbf)[i] = r; return;
  }
  i -= S4;
  if (i < S5) {
    float4 v = ((const float4*)ea)[i];
    bf16x4 r; r[0] = (__bf16)v.x; r[1] = (__bf16)v.y; r[2] = (__bf16)v.z; r[3] = (__bf16)v.w;
    ((bf16x4*)eabf)[i] = r; return;
  }
}

// ---------------- MFMA GEMM, 128x128 tile, dbuf 1-barrier K-loop ----------------
template <int RES, int OBF, int STATS, int ESCAT>
__global__ __launch_bounds__(256, 2)
void k_gemm(const __bf16* __restrict__ A, const __bf16* __restrict__ BT,
            const float* __restrict__ bias, const float* __restrict__ R,
            float* __restrict__ Cf, __bf16* __restrict__ Cb,
            const int* __restrict__ posmap, float2* __restrict__ pstats,
            int M, int Nn, int K) {
  __shared__ __bf16 lsA[2][4096];
  __shared__ __bf16 lsB[2][4096];
  __shared__ float sm[32][132];
  __shared__ float sbias[128];
  __shared__ float2 pst4[4][32];
  const int tid  = threadIdx.x;
  const int lane = tid & 63;
  const int wave = tid >> 6;
  const int ntn  = Nn >> 7;
  const int bid  = (int)blockIdx.x;
  const int bn   = (bid >> 3) % ntn;                 // XCD swizzle
  const int bm   = (bid & 7) + ((bid >> 3) / ntn) * 8;
  const size_t row0 = (size_t)bm * 128, col0 = (size_t)bn * 128;
  const int wr = (wave >> 1) * 64, wc = (wave & 1) * 64;
  const int ks = lane >> 4, fr = lane & 15;

  f32x4 acc[4][4] = {};

  const int s1 = tid, s2 = tid + 256;
  const int r1 = s1 & 127, ks1 = s1 >> 7;
  const int r2 = s2 & 127, ks2 = s2 >> 7;

  auto stage = [&](int buf, int k0) {
    gl_lds16(A  + (row0 + r1) * K + k0 + ks1 * 8, &lsA[buf][s1 * 8]);
    gl_lds16(A  + (row0 + r2) * K + k0 + ks2 * 8, &lsA[buf][s2 * 8]);
    gl_lds16(BT + (col0 + r1) * K + k0 + ks1 * 8, &lsB[buf][s1 * 8]);
    gl_lds16(BT + (col0 + r2) * K + k0 + ks2 * 8, &lsB[buf][s2 * 8]);
  };

  const int nk = K / 32;
  stage(0, 0);
  __syncthreads();
  int cur = 0;
  for (int t = 0; t < nk; t++) {
    if (t + 1 < nk) stage(cur ^ 1, (t + 1) * 32);
    bf16x8 af[4], bfr[4];
    #pragma unroll
    for (int m = 0; m < 4; m++) af[m]  = *(const bf16x8*)&lsA[cur][(ks * 128 + wr + m * 16 + fr) * 8];
    #pragma unroll
    for (int n = 0; n < 4; n++) bfr[n] = *(const bf16x8*)&lsB[cur][(ks * 128 + wc + n * 16 + fr) * 8];
    #pragma unroll
    for (int m = 0; m < 4; m++)
      #pragma unroll
      for (int n = 0; n < 4; n++)
        acc[m][n] = __builtin_amdgcn_mfma_f32_16x16x32_bf16(af[m], bfr[n], acc[m][n], 0, 0, 0);
    __syncthreads();
    cur ^= 1;
  }

  // ---- coalesced epilogue (LDS-transposed) ----
  if (tid < 128) sbias[tid] = bias[col0 + tid];
  const int fq = ks;
  const int rbase = (wave >> 1) * 16 + fq * 4;
  const int rr = tid >> 3, cs = (tid & 7) * 16;
  #pragma unroll
  for (int m = 0; m < 4; m++) {
    if (m) __syncthreads();
    #pragma unroll
    for (int n = 0; n < 4; n++)
      #pragma unroll
      for (int r = 0; r < 4; r++)
        sm[rbase + r][wc + n * 16 + fr] = acc[m][n][r];
    __syncthreads();
    const size_t lrow = ((rr & 16) ? 64 : 0) + m * 16 + (rr & 15);
    const size_t grow = row0 + lrow;
    float v[16];
    #pragma unroll
    for (int j = 0; j < 16; j++) v[j] = sm[rr][cs + j] + sbias[cs + j];
    if (STATS) {
      float ssum = 0.f, ssq = 0.f;
      #pragma unroll
      for (int j = 0; j < 16; j++) { ssum += v[j]; ssq += v[j] * v[j]; }
      #pragma unroll
      for (int o = 1; o < 8; o <<= 1) {
        ssum += __shfl_xor(ssum, o);
        ssq  += __shfl_xor(ssq, o);
      }
      if ((tid & 7) == 0) pst4[m][rr].x = ssum, pst4[m][rr].y = ssq;
    }
    const size_t gbase = grow * Nn + col0 + cs;
    if (RES) {
      #pragma unroll
      for (int j = 0; j < 16; j += 4) {
        const float4 rv = *(const float4*)&R[gbase + j];
        v[j] += rv.x; v[j + 1] += rv.y; v[j + 2] += rv.z; v[j + 3] += rv.w;
      }
    }
    if (OBF == 0 || OBF == 2) {
      #pragma unroll
      for (int j = 0; j < 16; j += 4) {
        float4 o; o.x = v[j]; o.y = v[j + 1]; o.z = v[j + 2]; o.w = v[j + 3];
        *(float4*)&Cf[gbase + j] = o;
      }
    }
    if (OBF == 1 || OBF == 2) {
      const size_t crow = ESCAT ? (size_t)posmap[grow] : grow;
      const size_t cbase = crow * Nn + col0 + cs;
      bf16x8 o0, o1;
      #pragma unroll
      for (int j = 0; j < 8; j++) { o0[j] = (__bf16)v[j]; o1[j] = (__bf16)v[8 + j]; }
      *(bf16x8*)&Cb[cbase] = o0;
      *(bf16x8*)&Cb[cbase + 8] = o1;
    }
  }
  if (STATS) {
    __syncthreads();
    if (tid < 128) {
      const int lr = tid;
      const int hi = lr >> 6, m2 = (lr >> 4) & 3, rl = lr & 15;
      pstats[(row0 + lr) * ntn + bn] = pst4[m2][(hi << 4) | rl];
    }
  }
}

// ---------------- GEMM2: h = relu(LN_512(c1)) @ w2 + b2 (+R), T14 A-staging ----
template <int RES>
__global__ __launch_bounds__(256, 2)
void k_gemm2(const __bf16* __restrict__ c1b, const __bf16* __restrict__ BT,
             const float* __restrict__ bias, const float* __restrict__ R,
             const float2* __restrict__ pstats, const float* __restrict__ gamma,
             const float* __restrict__ beta, float* __restrict__ Cf, int Nn) {
  constexpr int K = HD2;
  __shared__ __bf16 lsA[2][4096];
  __shared__ __bf16 lsB[2][4096];
  __shared__ float sm[32][132];
  __shared__ float sbias[128];
  __shared__ float smu[128], sinv[128];
  __shared__ float sg[512], sb[512];
  const int tid  = threadIdx.x;
  const int lane = tid & 63;
  const int wave = tid >> 6;
  const int ntn  = Nn >> 7;
  const int bid  = (int)blockIdx.x;
  const int bn   = (bid >> 3) % ntn;
  const int bm   = (bid & 7) + ((bid >> 3) / ntn) * 8;
  const size_t row0 = (size_t)bm * 128, col0 = (size_t)bn * 128;
  const int wr = (wave >> 1) * 64, wc = (wave & 1) * 64;
  const int ks = lane >> 4, fr = lane & 15;

  if (tid < 128) {
    const float4* pp = (const float4*)&pstats[(row0 + tid) * 4];
    const float4 q0 = pp[0], q1 = pp[1];
    const float su = q0.x + q0.z + q1.x + q1.z;
    const float sq = q0.y + q0.w + q1.y + q1.w;
    const float mu = su * (1.f / K);
    const float var = sq * (1.f / K) - mu * mu;
    smu[tid] = mu;
    sinv[tid] = rsqrtf(var + 1e-5f);
  }
  sg[tid] = gamma[tid]; sg[tid + 256] = gamma[tid + 256];
  sb[tid] = beta[tid];  sb[tid + 256] = beta[tid + 256];
  __syncthreads();

  const int s1 = tid, s2 = tid + 256;
  const int r1 = s1 & 127, ks1 = s1 >> 7;
  const int r2 = s2 & 127, ks2 = s2 >> 7;
  const float mu1 = smu[r1], iv1 = sinv[r1];
  f32x4 acc[4][4] = {};

  auto stageB = [&](int buf, int k0) {
    gl_lds16(BT + (col0 + r1) * K + k0 + ks1 * 8, &lsB[buf][s1 * 8]);
    gl_lds16(BT + (col0 + r2) * K + k0 + ks2 * 8, &lsB[buf][s2 * 8]);
  };
  auto loadA = [&](int k0, bf16x8& a0, bf16x8& a1v) {
    a0  = *(const bf16x8*)&c1b[(row0 + r1) * K + k0 + ks1 * 8];
    a1v = *(const bf16x8*)&c1b[(row0 + r2) * K + k0 + ks2 * 8];
  };
  auto writeA = [&](int buf, int k0, const bf16x8& a0, const bf16x8& a1v) {
    const int kb1 = k0 + ks1 * 8, kb2 = k0 + ks2 * 8;
    bf16x8 o0, o1;
    #pragma unroll
    for (int j = 0; j < 8; j++) {
      const float f0 = ((float)a0[j]  - mu1) * iv1 * sg[kb1 + j] + sb[kb1 + j];
      const float f1 = ((float)a1v[j] - mu1) * iv1 * sg[kb2 + j] + sb[kb2 + j];
      o0[j] = (__bf16)fmaxf(f0, 0.f);
      o1[j] = (__bf16)fmaxf(f1, 0.f);
    }
    *(bf16x8*)&lsA[buf][s1 * 8] = o0;
    *(bf16x8*)&lsA[buf][s2 * 8] = o1;
  };

  const int nk = K / 32;
  {
    bf16x8 a0, a1v;
    loadA(0, a0, a1v);
    stageB(0, 0);
    writeA(0, 0, a0, a1v);
  }
  __syncthreads();
  int cur = 0;
  for (int t = 0; t < nk; t++) {
    bf16x8 a0, a1v;
    const bool more = (t + 1 < nk);
    if (more) {
      stageB(cur ^ 1, (t + 1) * 32);
      loadA((t + 1) * 32, a0, a1v);
    }
    bf16x8 af[4], bfr[4];
    #pragma unroll
    for (int m = 0; m < 4; m++) af[m]  = *(const bf16x8*)&lsA[cur][(ks * 128 + wr + m * 16 + fr) * 8];
    #pragma unroll
    for (int n = 0; n < 4; n++) bfr[n] = *(const bf16x8*)&lsB[cur][(ks * 128 + wc + n * 16 + fr) * 8];
    #pragma unroll
    for (int m = 0; m < 4; m++)
      #pragma unroll
      for (int n = 0; n < 4; n++)
        acc[m][n] = __builtin_amdgcn_mfma_f32_16x16x32_bf16(af[m], bfr[n], acc[m][n], 0, 0, 0);
    if (more) writeA(cur ^ 1, (t + 1) * 32, a0, a1v);
    __syncthreads();
    cur ^= 1;
  }

  if (tid < 128) sbias[tid] = bias[col0 + tid];
  const int fq = ks;
  const int rbase = (wave >> 1) * 16 + fq * 4;
  const int rr = tid >> 3, cs = (tid & 7) * 16;
  #pragma unroll
  for (int m = 0; m < 4; m++) {
    if (m) __syncthreads();
    #pragma unroll
    for (int n = 0; n < 4; n++)
      #pragma unroll
      for (int r = 0; r < 4; r++)
        sm[rbase + r][wc + n * 16 + fr] = acc[m][n][r];
    __syncthreads();
    const size_t grow = row0 + ((rr & 16) ? 64 : 0) + m * 16 + (rr & 15);
    const size_t gbase = grow * Nn + col0 + cs;
    float v[16];
    #pragma unroll
    for (int j = 0; j < 16; j++) v[j] = sm[rr][cs + j] + sbias[cs + j];
    if (RES) {
      #pragma unroll
      for (int j = 0; j < 16; j += 4) {
        const float4 rv = *(const float4*)&R[gbase + j];
        v[j] += rv.x; v[j + 1] += rv.y; v[j + 2] += rv.z; v[j + 3] += rv.w;
      }
    }
    #pragma unroll
    for (int j = 0; j < 16; j += 4) {
      float4 o; o.x = v[j]; o.y = v[j + 1]; o.z = v[j + 2]; o.w = v[j + 3];
      *(float4*)&Cf[gbase + j] = o;
    }
  }
}

// ---------------- wave-per-node softmax aggregation (8-deep groups) ----------------
__global__ __launch_bounds__(256)
void k_msg(const __bf16* __restrict__ zb, const __bf16* __restrict__ ecsr,
           const int* __restrict__ row_start, const int* __restrict__ deg,
           const int2* __restrict__ csr_es, const float* __restrict__ tvec,
           int layer, __bf16* __restrict__ a1) {
  const int wv   = __builtin_amdgcn_readfirstlane(threadIdx.x >> 6);
  const int lane = threadIdx.x & 63;
  const int node = blockIdx.x * 4 + wv;
  const int st = __builtin_amdgcn_readfirstlane(row_start[node]);
  const int dg = __builtin_amdgcn_readfirstlane(deg[node]);
  const float t = tvec[layer];
  const int f0 = lane * 4;

  int my_src = 0;
  if (lane < dg) my_src = csr_es[st + lane].y;
  const bf16x4 sv = *(const bf16x4*)&zb[(size_t)node * HD + f0];

  float den[4] = {0.f, 0.f, 0.f, 0.f}, agg[4] = {0.f, 0.f, 0.f, 0.f};
  const int dmain = dg < 64 ? dg : 64;
  int j = 0;
  for (; j + 8 <= dmain; j += 8) {
    bf16x4 zv[8], ev[8];
    #pragma unroll
    for (int u = 0; u < 8; u++) {
      const int sn = __builtin_amdgcn_readlane(my_src, j + u);
      zv[u] = *(const bf16x4*)&zb[(size_t)sn * HD + f0];
      ev[u] = *(const bf16x4*)&ecsr[(size_t)(st + j + u) * HD + f0];
    }
    #pragma unroll
    for (int u = 0; u < 8; u++)
      #pragma unroll
      for (int q = 0; q < 4; q++) {
        const float m  = fmaxf((float)zv[u][q] + (float)ev[u][q], 0.f) + 1e-7f;
        const float ex = __expf(m * t);
        den[q] += ex;
        agg[q] += m * ex;
      }
  }
  for (; j + 4 <= dmain; j += 4) {
    bf16x4 zv[4], ev[4];
    #pragma unroll
    for (int u = 0; u < 4; u++) {
      const int sn = __builtin_amdgcn_readlane(my_src, j + u);
      zv[u] = *(const bf16x4*)&zb[(size_t)sn * HD + f0];
      ev[u] = *(const bf16x4*)&ecsr[(size_t)(st + j + u) * HD + f0];
    }
    #pragma unroll
    for (int u = 0; u < 4; u++)
      #pragma unroll
      for (int q = 0; q < 4; q++) {
        const float m  = fmaxf((float)zv[u][q] + (float)ev[u][q], 0.f) + 1e-7f;
        const float ex = __expf(m * t);
        den[q] += ex;
        agg[q] += m * ex;
      }
  }
  for (; j < dmain; j++) {
    const int sn = __builtin_amdgcn_readlane(my_src, j);
    const bf16x4 zv = *(const bf16x4*)&zb[(size_t)sn * HD + f0];
    const bf16x4 ev = *(const bf16x4*)&ecsr[(size_t)(st + j) * HD + f0];
    #pragma unroll
    for (int q = 0; q < 4; q++) {
      const float m  = fmaxf((float)zv[q] + (float)ev[q], 0.f) + 1e-7f;
      const float ex = __expf(m * t);
      den[q] += ex;
      agg[q] += m * ex;
    }
  }
  for (int jj = 64; jj < dg; jj++) {  // cold path
    const int2 pr = csr_es[st + jj];
    const bf16x4 zv = *(const bf16x4*)&zb[(size_t)pr.y * HD + f0];
    const bf16x4 ev = *(const bf16x4*)&ecsr[(size_t)(st + jj) * HD + f0];
    #pragma unroll
    for (int q = 0; q < 4; q++) {
      const float m  = fmaxf((float)zv[q] + (float)ev[q], 0.f) + 1e-7f;
      const float ex = __expf(m * t);
      den[q] += ex;
      agg[q] += m * ex;
    }
  }
  bf16x4 r;
  #pragma unroll
  for (int q = 0; q < 4; q++) {
    const float res = (dg > 0) ? agg[q] / (den[q] + 1e-16f) : 0.f;
    r[q] = (__bf16)(res + (float)sv[q]);
  }
  *(bf16x4*)&a1[(size_t)node * HD + f0] = r;
}

// ---------------- LN: zb = bf16(relu(LN_256(h))) ----------------
__global__ __launch_bounds__(256)
void k_prenorm(const float* __restrict__ h, const float* __restrict__ g,
               const float* __restrict__ b, __bf16* __restrict__ zb) {
  const int row  = blockIdx.x * 4 + (threadIdx.x >> 6);
  const int lane = threadIdx.x & 63;
  const float4 v = *(const float4*)&h[(size_t)row * HD + lane * 4];
  float s = v.x + v.y + v.z + v.w;
  for (int o = 1; o < 64; o <<= 1) s += __shfl_xor(s, o);
  const float mu = s * (1.f / HD);
  const float dx = v.x - mu, dy = v.y - mu, dz = v.z - mu, dw = v.w - mu;
  float q = dx * dx + dy * dy + dz * dz + dw * dw;
  for (int o = 1; o < 64; o <<= 1) q += __shfl_xor(q, o);
  const float inv = rsqrtf(q * (1.f / HD) + 1e-5f);
  const float4 gv = *(const float4*)&g[lane * 4];
  const float4 bv = *(const float4*)&b[lane * 4];
  bf16x4 r;
  r[0] = (__bf16)fmaxf(dx * inv * gv.x + bv.x, 0.f);
  r[1] = (__bf16)fmaxf(dy * inv * gv.y + bv.y, 0.f);
  r[2] = (__bf16)fmaxf(dz * inv * gv.z + bv.z, 0.f);
  r[3] = (__bf16)fmaxf(dw * inv * gv.w + bv.w, 0.f);
  *(bf16x4*)&zb[(size_t)row * HD + lane * 4] = r;
}

// ---------------- fused final LN + head ----------------
__global__ __launch_bounds__(256)
void k_headln(const float* __restrict__ h, const float* __restrict__ g,
              const float* __restrict__ b, const float* __restrict__ lw,
              const float* __restrict__ lb, float* __restrict__ out) {
  __shared__ float slw[256 * 16];   // [k][c]
  __shared__ float srow[16 * 256];
  const int t = threadIdx.x;
  const size_t row0 = (size_t)blockIdx.x * 16;
  #pragma unroll
  for (int j = 0; j < 16; j++) slw[j * 256 + t] = lw[j * 256 + t];
  const int rl = t >> 4, col = t & 15;
  float v[16];
  float s = 0.f, sq = 0.f;
  #pragma unroll
  for (int j = 0; j < 16; j += 4) {
    const float4 hv = *(const float4*)&h[(row0 + rl) * HD + col * 16 + j];
    v[j] = hv.x; v[j + 1] = hv.y; v[j + 2] = hv.z; v[j + 3] = hv.w;
  }
  #pragma unroll
  for (int j = 0; j < 16; j++) { s += v[j]; sq += v[j] * v[j]; }
  #pragma unroll
  for (int o = 1; o < 16; o <<= 1) { s += __shfl_xor(s, o); sq += __shfl_xor(sq, o); }
  const float mu = s * (1.f / HD);
  const float inv = rsqrtf(sq * (1.f / HD) - mu * mu + 1e-5f);
  #pragma unroll
  for (int j = 0; j < 16; j += 4) {
    const float4 gv = *(const float4*)&g[col * 16 + j];
    const float4 bv = *(const float4*)&b[col * 16 + j];
    srow[rl * 256 + col * 16 + j]     = fmaxf((v[j]     - mu) * inv * gv.x + bv.x, 0.f);
    srow[rl * 256 + col * 16 + j + 1] = fmaxf((v[j + 1] - mu) * inv * gv.y + bv.y, 0.f);
    srow[rl * 256 + col * 16 + j + 2] = fmaxf((v[j + 2] - mu) * inv * gv.z + bv.z, 0.f);
    srow[rl * 256 + col * 16 + j + 3] = fmaxf((v[j + 3] - mu) * inv * gv.w + bv.w, 0.f);
  }
  __syncthreads();
  float acc = lb[col];
  #pragma unroll 8
  for (int k = 0; k < 256; k++) acc += srow[rl * 256 + k] * slw[k * 16 + col];
  out[(row0 + rl) * 16 + col] = acc;
}

// ---------------- host launch ----------------
extern "C" void kernel_launch(void* const* d_in, const int* in_sizes, int n_in,
                              void* d_out, int out_size, void* d_ws, size_t ws_size,
                              hipStream_t stream) {
  const float* x     = (const float*)d_in[0];
  const int*   ei    = (const int*)d_in[1];
  const float* ea    = (const float*)d_in[2];
  const float* enc_w = (const float*)d_in[3];
  const float* enc_b = (const float*)d_in[4];
  const float* ee_w  = (const float*)d_in[5];
  const float* ee_b  = (const float*)d_in[6];
  const float* w1    = (const float*)d_in[7];
  const float* b1    = (const float*)d_in[8];
  const float* lng   = (const float*)d_in[9];
  const float* lnb   = (const float*)d_in[10];
  const float* w2    = (const float*)d_in[11];
  const float* b2    = (const float*)d_in[12];
  const float* tvec  = (const float*)d_in[13];
  const float* ng    = (const float*)d_in[14];
  const float* nb    = (const float*)d_in[15];
  const float* lin_w = (const float*)d_in[16];
  const float* lin_b = (const float*)d_in[17];

  uint8_t* p = (uint8_t*)d_ws;
  auto alloc = [&](size_t bytes) { uint8_t* r = p; p += (bytes + 255) & ~(size_t)255; return r; };
  __bf16* e_csr  = (__bf16*)alloc((size_t)NE * HD * 2);
  float*  h      = (float*) alloc((size_t)NN * HD * 4);
  __bf16* hb     = (__bf16*)alloc((size_t)NN * HD * 2);
  __bf16* zb     = (__bf16*)alloc((size_t)NN * HD * 2);
  __bf16* a1     = (__bf16*)alloc((size_t)NN * HD * 2);
  __bf16* c1b    = (__bf16*)alloc((size_t)NN * HD2 * 2);
  float2* pstats = (float2*)alloc((size_t)NN * 4 * 8);
  __bf16* xbf    = (__bf16*)alloc((size_t)NN * DIN * 2);
  __bf16* eabf   = (__bf16*)alloc((size_t)NE * DE * 2);
  __bf16* enc_wT = (__bf16*)alloc((size_t)HD * DIN * 2);
  __bf16* ee_wT  = (__bf16*)alloc((size_t)HD * DE * 2);
  __bf16* w1T    = (__bf16*)alloc((size_t)4 * HD2 * HD * 2);
  __bf16* w2T    = (__bf16*)alloc((size_t)4 * HD * HD2 * 2);
  int* deg       = (int*)alloc((size_t)NN * 4);
  int* cursor    = (int*)alloc((size_t)NN * 4);   // contiguous with deg -> one memset
  int* row_start = (int*)alloc((size_t)NN * 4);
  int* posmap    = (int*)alloc((size_t)NE * 4);
  int2* csr_es   = (int2*)alloc((size_t)NE * 8);

  const int* srcp = ei;
  const int* dstp = ei + NE;

  hipMemsetAsync(deg, 0, (size_t)NN * 8, stream);  // deg + cursor
  k_hist<<<NE / 256, 256, 0, stream>>>(dstp, deg);
  k_scan<<<1, 1024, 0, stream>>>(deg, row_start);
  k_scatter<<<NE / 256, 256, 0, stream>>>(srcp, dstp, row_start, cursor, csr_es);
  k_sortw<<<NN / 4, 256, 0, stream>>>(row_start, deg, csr_es, posmap);

  const int prep_total = DIN * HD + DE * HD + 4 * HD * HD2 + 4 * HD2 * HD +
                         NN * DIN / 4 + NE * DE / 4;
  k_prep<<<(prep_total + 255) / 256, 256, 0, stream>>>(enc_w, ee_w, w1, w2, x, ea,
                                                       enc_wT, ee_wT, w1T, w2T, xbf, eabf);

  // node encoder: h(f32) + hb(bf16)
  k_gemm<0, 2, 0, 0><<<(NN / 128) * (HD / 128), 256, 0, stream>>>(
      xbf, enc_wT, enc_b, nullptr, h, hb, nullptr, nullptr, NN, HD, DIN);
  // edge encoder -> e_csr (CSR-position-ordered rows)
  k_gemm<0, 1, 0, 1><<<(NE / 128) * (HD / 128), 256, 0, stream>>>(
      eabf, ee_wT, ee_b, nullptr, nullptr, e_csr, posmap, nullptr, NE, HD, DE);

  for (int i = 0; i < 4; i++) {
    const __bf16* zin = (i == 0) ? hb : zb;
    k_msg<<<NN / 4, 256, 0, stream>>>(zin, e_csr, row_start, deg, csr_es, tvec, i, a1);
    // GEMM1: c1b = bf16(a1 @ w1 + b1) + per-row stats
    k_gemm<0, 1, 1, 0><<<(NN / 128) * (HD2 / 128), 256, 0, stream>>>(
        a1, w1T + (size_t)i * HD2 * HD, b1 + (size_t)i * HD2, nullptr, nullptr, c1b,
        nullptr, pstats, NN, HD2, HD);
    // GEMM2 (fused LN512+ReLU on A): h = relu(LN(c1)) @ w2 + b2 (+h)
    if (i == 0)
      k_gemm2<0><<<(NN / 128) * (HD / 128), 256, 0, stream>>>(
          c1b, w2T + (size_t)i * HD * HD2, b2 + (size_t)i * HD, nullptr, pstats,
          lng + (size_t)i * HD2, lnb + (size_t)i * HD2, h, HD);
    else
      k_gemm2<1><<<(NN / 128) * (HD / 128), 256, 0, stream>>>(
          c1b, w2T + (size_t)i * HD * HD2, b2 + (size_t)i * HD, h, pstats,
          lng + (size_t)i * HD2, lnb + (size_t)i * HD2, h, HD);
    if (i < 3)
      k_prenorm<<<NN / 4, 256, 0, stream>>>(h, ng + (size_t)(i + 1) * HD,
                                            nb + (size_t)(i + 1) * HD, zb);
  }

  k_headln<<<NN / 16, 256, 0, stream>>>(h, ng, nb, lin_w, lin_b, (float*)d_out);
}

// Round 10
// 374.765 us; speedup vs baseline: 1.2447x; 1.0139x over previous
//
#include <hip/hip_runtime.h>
#include <stdint.h>
#include <math.h>

// DeeperGNN forward on MI355X.
// R10: LDS-union arenas in GEMMs (32/37 KB), launch_bounds(256,3) -> 3 blocks/CU,
// hist merged into prep. Numerics bit-identical to R9.

typedef __bf16 bf16x8 __attribute__((ext_vector_type(8)));
typedef __bf16 bf16x4 __attribute__((ext_vector_type(4)));
typedef float  f32x4  __attribute__((ext_vector_type(4)));

constexpr int NN   = 16384;   // nodes
constexpr int NE   = 131072;  // edges
constexpr int DIN  = 128;
constexpr int DE   = 64;
constexpr int HD   = 256;
constexpr int HD2  = 512;

__device__ __forceinline__ void gl_lds16(const __bf16* g, __bf16* l) {
  __builtin_amdgcn_global_load_lds((const __attribute__((address_space(1))) void*)g,
                                   (__attribute__((address_space(3))) void*)l, 16, 0, 0);
}

// ---------------- CSR build ----------------
__global__ __launch_bounds__(1024) void k_scan(const int* __restrict__ deg,
                                               int* __restrict__ row_start) {
  __shared__ int part[1024];
  const int t = threadIdx.x;
  const int base = t * 16;
  int loc[16];
  int s = 0;
  #pragma unroll
  for (int i = 0; i < 16; i++) { loc[i] = s; s += deg[base + i]; }
  part[t] = s;
  __syncthreads();
  for (int off = 1; off < 1024; off <<= 1) {
    int v = (t >= off) ? part[t - off] : 0;
    __syncthreads();
    part[t] += v;
    __syncthreads();
  }
  const int excl = (t == 0) ? 0 : part[t - 1];
  #pragma unroll
  for (int i = 0; i < 16; i++) row_start[base + i] = excl + loc[i];
}

__global__ void k_scatter(const int* __restrict__ src, const int* __restrict__ dst,
                          const int* __restrict__ row_start, int* __restrict__ cursor,
                          int2* __restrict__ csr_es) {
  int e = blockIdx.x * 256 + threadIdx.x;
  if (e >= NE) return;
  const int d = dst[e];
  const int p = atomicAdd(&cursor[d], 1);
  csr_es[row_start[d] + p] = make_int2(e, src[e]);
}

// wave-parallel canonical sort: one wave per node; lane's rank = #(smaller eids).
__global__ __launch_bounds__(256)
void k_sortw(const int* __restrict__ row_start, const int* __restrict__ deg,
             int2* __restrict__ csr_es, int* __restrict__ posmap) {
  const int wv   = threadIdx.x >> 6;
  const int lane = threadIdx.x & 63;
  const int node = blockIdx.x * 4 + wv;
  if (node >= NN) return;
  const int st = __builtin_amdgcn_readfirstlane(row_start[node]);
  const int dg = __builtin_amdgcn_readfirstlane(deg[node]);
  if (dg <= 1) {
    if (dg == 1 && lane == 0) posmap[csr_es[st].x] = st;
    return;
  }
  if (dg <= 64) {
    int2 pr = make_int2(0x7fffffff, 0);
    if (lane < dg) pr = csr_es[st + lane];
    int rank = 0;
    for (int j = 0; j < dg; j++) {
      const int ej = __builtin_amdgcn_readlane(pr.x, j);
      if (lane < dg && ej < pr.x) rank++;
    }
    if (lane < dg) {
      csr_es[st + rank] = pr;
      posmap[pr.x] = st + rank;
    }
  } else if (lane == 0) {  // cold fallback
    for (int a = 1; a < dg; a++) {
      int2 k = csr_es[st + a];
      int b = a - 1;
      while (b >= 0 && csr_es[st + b].x > k.x) { csr_es[st + b + 1] = csr_es[st + b]; b--; }
      csr_es[st + b + 1] = k;
    }
    for (int a = 0; a < dg; a++) posmap[csr_es[st + a].x] = st + a;
  }
}

// ---------------- merged prep: weight transposes + casts + degree histogram ----------------
__global__ void k_prep(const float* __restrict__ enc_w, const float* __restrict__ ee_w,
                       const float* __restrict__ w1, const float* __restrict__ w2,
                       const float* __restrict__ x, const float* __restrict__ ea,
                       const int* __restrict__ dst, int* __restrict__ deg,
                       __bf16* __restrict__ enc_wT, __bf16* __restrict__ ee_wT,
                       __bf16* __restrict__ w1T, __bf16* __restrict__ w2T,
                       __bf16* __restrict__ xbf, __bf16* __restrict__ eabf) {
  int i = blockIdx.x * 256 + threadIdx.x;
  const int S0 = DIN * HD, S1 = DE * HD, S2 = 4 * HD * HD2, S3 = 4 * HD2 * HD;
  const int S4 = NN * DIN / 4, S5 = NE * DE / 4;
  if (i < S0) { int k = i / HD, n = i % HD; enc_wT[n * DIN + k] = (__bf16)enc_w[i]; return; }
  i -= S0;
  if (i < S1) { int k = i / HD, n = i % HD; ee_wT[n * DE + k] = (__bf16)ee_w[i]; return; }
  i -= S1;
  if (i < S2) {
    int l = i / (HD * HD2), r = i % (HD * HD2), k = r / HD2, n = r % HD2;
    w1T[(size_t)l * HD * HD2 + (size_t)n * HD + k] = (__bf16)w1[i]; return;
  }
  i -= S2;
  if (i < S3) {
    int l = i / (HD2 * HD), r = i % (HD2 * HD), k = r / HD, n = r % HD;
    w2T[(size_t)l * HD2 * HD + (size_t)n * HD2 + k] = (__bf16)w2[i]; return;
  }
  i -= S3;
  if (i < S4) {
    float4 v = ((const float4*)x)[i];
    bf16x4 r; r[0] = (__bf16)v.x; r[1] = (__bf16)v.y; r[2] = (__bf16)v.z; r[3] = (__bf16)v.w;
    ((bf16x4*)xbf)[i] = r; return;
  }
  i -= S4;
  if (i < S5) {
    float4 v = ((const float4*)ea)[i];
    bf16x4 r; r[0] = (__bf16)v.x; r[1] = (__bf16)v.y; r[2] = (__bf16)v.z; r[3] = (__bf16)v.w;
    ((bf16x4*)eabf)[i] = r; return;
  }
  i -= S5;
  if (i < NE) { atomicAdd(&deg[dst[i]], 1); return; }   // fused histogram
}

// ---------------- MFMA GEMM, 128x128 tile, dbuf 1-barrier K-loop, LDS union ----
template <int RES, int OBF, int STATS, int ESCAT>
__global__ __launch_bounds__(256, 3)
void k_gemm(const __bf16* __restrict__ A, const __bf16* __restrict__ BT,
            const float* __restrict__ bias, const float* __restrict__ R,
            float* __restrict__ Cf, __bf16* __restrict__ Cb,
            const int* __restrict__ posmap, float2* __restrict__ pstats,
            int M, int Nn, int K) {
  __shared__ __attribute__((aligned(16))) char smem[32768];
  __bf16* lsA0 = (__bf16*)smem;                    // K-loop: 2x8KB A
  __bf16* lsA1 = (__bf16*)(smem + 8192);
  __bf16* lsB0 = (__bf16*)(smem + 16384);          //         2x8KB B
  __bf16* lsB1 = (__bf16*)(smem + 24576);
  float (*sm)[129] = (float(*)[129])smem;          // epilogue overlay: 16.5KB
  float* sbias     = (float*)(smem + 16512);       // 512B
  float2 (*pst4)[32] = (float2(*)[32])(smem + 17024);  // 1KB
  const int tid  = threadIdx.x;
  const int lane = tid & 63;
  const int wave = tid >> 6;
  const int ntn  = Nn >> 7;
  const int bid  = (int)blockIdx.x;
  const int bn   = (bid >> 3) % ntn;                 // XCD swizzle
  const int bm   = (bid & 7) + ((bid >> 3) / ntn) * 8;
  const size_t row0 = (size_t)bm * 128, col0 = (size_t)bn * 128;
  const int wr = (wave >> 1) * 64, wc = (wave & 1) * 64;
  const int ks = lane >> 4, fr = lane & 15;

  f32x4 acc[4][4] = {};

  const int s1 = tid, s2 = tid + 256;
  const int r1 = s1 & 127, ks1 = s1 >> 7;
  const int r2 = s2 & 127, ks2 = s2 >> 7;

  auto stage = [&](__bf16* la, __bf16* lb, int k0) {
    gl_lds16(A  + (row0 + r1) * K + k0 + ks1 * 8, &la[s1 * 8]);
    gl_lds16(A  + (row0 + r2) * K + k0 + ks2 * 8, &la[s2 * 8]);
    gl_lds16(BT + (col0 + r1) * K + k0 + ks1 * 8, &lb[s1 * 8]);
    gl_lds16(BT + (col0 + r2) * K + k0 + ks2 * 8, &lb[s2 * 8]);
  };

  const int nk = K / 32;
  stage(lsA0, lsB0, 0);
  __syncthreads();
  for (int t = 0; t < nk; t++) {
    const __bf16* la = (t & 1) ? lsA1 : lsA0;
    const __bf16* lb = (t & 1) ? lsB1 : lsB0;
    if (t + 1 < nk) stage((t & 1) ? lsA0 : lsA1, (t & 1) ? lsB0 : lsB1, (t + 1) * 32);
    bf16x8 af[4], bfr[4];
    #pragma unroll
    for (int m = 0; m < 4; m++) af[m]  = *(const bf16x8*)&la[(ks * 128 + wr + m * 16 + fr) * 8];
    #pragma unroll
    for (int n = 0; n < 4; n++) bfr[n] = *(const bf16x8*)&lb[(ks * 128 + wc + n * 16 + fr) * 8];
    #pragma unroll
    for (int m = 0; m < 4; m++)
      #pragma unroll
      for (int n = 0; n < 4; n++)
        acc[m][n] = __builtin_amdgcn_mfma_f32_16x16x32_bf16(af[m], bfr[n], acc[m][n], 0, 0, 0);
    __syncthreads();
  }

  // ---- coalesced epilogue (LDS-transposed, overlays K-loop buffers) ----
  if (tid < 128) sbias[tid] = bias[col0 + tid];
  const int fq = ks;
  const int rbase = (wave >> 1) * 16 + fq * 4;
  const int rr = tid >> 3, cs = (tid & 7) * 16;
  #pragma unroll
  for (int m = 0; m < 4; m++) {
    if (m) __syncthreads();
    #pragma unroll
    for (int n = 0; n < 4; n++)
      #pragma unroll
      for (int r = 0; r < 4; r++)
        sm[rbase + r][wc + n * 16 + fr] = acc[m][n][r];
    __syncthreads();
    const size_t lrow = ((rr & 16) ? 64 : 0) + m * 16 + (rr & 15);
    const size_t grow = row0 + lrow;
    float v[16];
    #pragma unroll
    for (int j = 0; j < 16; j++) v[j] = sm[rr][cs + j] + sbias[cs + j];
    if (STATS) {
      float ssum = 0.f, ssq = 0.f;
      #pragma unroll
      for (int j = 0; j < 16; j++) { ssum += v[j]; ssq += v[j] * v[j]; }
      #pragma unroll
      for (int o = 1; o < 8; o <<= 1) {
        ssum += __shfl_xor(ssum, o);
        ssq  += __shfl_xor(ssq, o);
      }
      if ((tid & 7) == 0) pst4[m][rr].x = ssum, pst4[m][rr].y = ssq;
    }
    const size_t gbase = grow * Nn + col0 + cs;
    if (RES) {
      #pragma unroll
      for (int j = 0; j < 16; j += 4) {
        const float4 rv = *(const float4*)&R[gbase + j];
        v[j] += rv.x; v[j + 1] += rv.y; v[j + 2] += rv.z; v[j + 3] += rv.w;
      }
    }
    if (OBF == 0 || OBF == 2) {
      #pragma unroll
      for (int j = 0; j < 16; j += 4) {
        float4 o; o.x = v[j]; o.y = v[j + 1]; o.z = v[j + 2]; o.w = v[j + 3];
        *(float4*)&Cf[gbase + j] = o;
      }
    }
    if (OBF == 1 || OBF == 2) {
      const size_t crow = ESCAT ? (size_t)posmap[grow] : grow;
      const size_t cbase = crow * Nn + col0 + cs;
      bf16x8 o0, o1;
      #pragma unroll
      for (int j = 0; j < 8; j++) { o0[j] = (__bf16)v[j]; o1[j] = (__bf16)v[8 + j]; }
      *(bf16x8*)&Cb[cbase] = o0;
      *(bf16x8*)&Cb[cbase + 8] = o1;
    }
  }
  if (STATS) {
    __syncthreads();
    if (tid < 128) {
      const int lr = tid;
      const int hi = lr >> 6, m2 = (lr >> 4) & 3, rl = lr & 15;
      pstats[(row0 + lr) * ntn + bn] = pst4[m2][(hi << 4) | rl];
    }
  }
}

// ---------------- GEMM2: h = relu(LN_512(c1)) @ w2 + b2 (+R), T14 + LDS union ----
template <int RES>
__global__ __launch_bounds__(256, 3)
void k_gemm2(const __bf16* __restrict__ c1b, const __bf16* __restrict__ BT,
             const float* __restrict__ bias, const float* __restrict__ R,
             const float2* __restrict__ pstats, const float* __restrict__ gamma,
             const float* __restrict__ beta, float* __restrict__ Cf, int Nn) {
  constexpr int K = HD2;
  // persistent region (live through K-loop): smu/sinv/sg/sb = 5120 B
  __shared__ __attribute__((aligned(16))) char smem[5120 + 32768];
  float* smu  = (float*)smem;              // 512
  float* sinv = (float*)(smem + 512);      // 512
  float* sg   = (float*)(smem + 1024);     // 2048
  float* sb   = (float*)(smem + 3072);     // 2048
  char* arena = smem + 5120;
  __bf16* lsA0 = (__bf16*)arena;
  __bf16* lsA1 = (__bf16*)(arena + 8192);
  __bf16* lsB0 = (__bf16*)(arena + 16384);
  __bf16* lsB1 = (__bf16*)(arena + 24576);
  float (*sm)[129] = (float(*)[129])arena;           // epilogue overlay
  float* sbias     = (float*)(arena + 16512);
  const int tid  = threadIdx.x;
  const int lane = tid & 63;
  const int wave = tid >> 6;
  const int ntn  = Nn >> 7;
  const int bid  = (int)blockIdx.x;
  const int bn   = (bid >> 3) % ntn;
  const int bm   = (bid & 7) + ((bid >> 3) / ntn) * 8;
  const size_t row0 = (size_t)bm * 128, col0 = (size_t)bn * 128;
  const int wr = (wave >> 1) * 64, wc = (wave & 1) * 64;
  const int ks = lane >> 4, fr = lane & 15;

  if (tid < 128) {
    const float4* pp = (const float4*)&pstats[(row0 + tid) * 4];
    const float4 q0 = pp[0], q1 = pp[1];
    const float su = q0.x + q0.z + q1.x + q1.z;
    const float sq = q0.y + q0.w + q1.y + q1.w;
    const float mu = su * (1.f / K);
    const float var = sq * (1.f / K) - mu * mu;
    smu[tid] = mu;
    sinv[tid] = rsqrtf(var + 1e-5f);
  }
  sg[tid] = gamma[tid]; sg[tid + 256] = gamma[tid + 256];
  sb[tid] = beta[tid];  sb[tid + 256] = beta[tid + 256];
  __syncthreads();

  const int s1 = tid, s2 = tid + 256;
  const int r1 = s1 & 127, ks1 = s1 >> 7;
  const int r2 = s2 & 127, ks2 = s2 >> 7;
  const float mu1 = smu[r1], iv1 = sinv[r1];
  f32x4 acc[4][4] = {};

  auto stageB = [&](__bf16* lb, int k0) {
    gl_lds16(BT + (col0 + r1) * K + k0 + ks1 * 8, &lb[s1 * 8]);
    gl_lds16(BT + (col0 + r2) * K + k0 + ks2 * 8, &lb[s2 * 8]);
  };
  auto loadA = [&](int k0, bf16x8& a0, bf16x8& a1v) {
    a0  = *(const bf16x8*)&c1b[(row0 + r1) * K + k0 + ks1 * 8];
    a1v = *(const bf16x8*)&c1b[(row0 + r2) * K + k0 + ks2 * 8];
  };
  auto writeA = [&](__bf16* la, int k0, const bf16x8& a0, const bf16x8& a1v) {
    const int kb1 = k0 + ks1 * 8, kb2 = k0 + ks2 * 8;
    bf16x8 o0, o1;
    #pragma unroll
    for (int j = 0; j < 8; j++) {
      const float f0 = ((float)a0[j]  - mu1) * iv1 * sg[kb1 + j] + sb[kb1 + j];
      const float f1 = ((float)a1v[j] - mu1) * iv1 * sg[kb2 + j] + sb[kb2 + j];
      o0[j] = (__bf16)fmaxf(f0, 0.f);
      o1[j] = (__bf16)fmaxf(f1, 0.f);
    }
    *(bf16x8*)&la[s1 * 8] = o0;
    *(bf16x8*)&la[s2 * 8] = o1;
  };

  const int nk = K / 32;
  {
    bf16x8 a0, a1v;
    loadA(0, a0, a1v);
    stageB(lsB0, 0);
    writeA(lsA0, 0, a0, a1v);
  }
  __syncthreads();
  for (int t = 0; t < nk; t++) {
    const __bf16* la = (t & 1) ? lsA1 : lsA0;
    const __bf16* lb = (t & 1) ? lsB1 : lsB0;
    bf16x8 a0, a1v;
    const bool more = (t + 1 < nk);
    if (more) {
      stageB((t & 1) ? lsB0 : lsB1, (t + 1) * 32);
      loadA((t + 1) * 32, a0, a1v);
    }
    bf16x8 af[4], bfr[4];
    #pragma unroll
    for (int m = 0; m < 4; m++) af[m]  = *(const bf16x8*)&la[(ks * 128 + wr + m * 16 + fr) * 8];
    #pragma unroll
    for (int n = 0; n < 4; n++) bfr[n] = *(const bf16x8*)&lb[(ks * 128 + wc + n * 16 + fr) * 8];
    #pragma unroll
    for (int m = 0; m < 4; m++)
      #pragma unroll
      for (int n = 0; n < 4; n++)
        acc[m][n] = __builtin_amdgcn_mfma_f32_16x16x32_bf16(af[m], bfr[n], acc[m][n], 0, 0, 0);
    if (more) writeA((t & 1) ? lsA0 : lsA1, (t + 1) * 32, a0, a1v);
    __syncthreads();
  }

  if (tid < 128) sbias[tid] = bias[col0 + tid];
  const int fq = ks;
  const int rbase = (wave >> 1) * 16 + fq * 4;
  const int rr = tid >> 3, cs = (tid & 7) * 16;
  #pragma unroll
  for (int m = 0; m < 4; m++) {
    if (m) __syncthreads();
    #pragma unroll
    for (int n = 0; n < 4; n++)
      #pragma unroll
      for (int r = 0; r < 4; r++)
        sm[rbase + r][wc + n * 16 + fr] = acc[m][n][r];
    __syncthreads();
    const size_t grow = row0 + ((rr & 16) ? 64 : 0) + m * 16 + (rr & 15);
    const size_t gbase = grow * Nn + col0 + cs;
    float v[16];
    #pragma unroll
    for (int j = 0; j < 16; j++) v[j] = sm[rr][cs + j] + sbias[cs + j];
    if (RES) {
      #pragma unroll
      for (int j = 0; j < 16; j += 4) {
        const float4 rv = *(const float4*)&R[gbase + j];
        v[j] += rv.x; v[j + 1] += rv.y; v[j + 2] += rv.z; v[j + 3] += rv.w;
      }
    }
    #pragma unroll
    for (int j = 0; j < 16; j += 4) {
      float4 o; o.x = v[j]; o.y = v[j + 1]; o.z = v[j + 2]; o.w = v[j + 3];
      *(float4*)&Cf[gbase + j] = o;
    }
  }
}

// ---------------- wave-per-node softmax aggregation (8-deep groups) ----------------
__global__ __launch_bounds__(256)
void k_msg(const __bf16* __restrict__ zb, const __bf16* __restrict__ ecsr,
           const int* __restrict__ row_start, const int* __restrict__ deg,
           const int2* __restrict__ csr_es, const float* __restrict__ tvec,
           int layer, __bf16* __restrict__ a1) {
  const int wv   = __builtin_amdgcn_readfirstlane(threadIdx.x >> 6);
  const int lane = threadIdx.x & 63;
  const int node = blockIdx.x * 4 + wv;
  const int st = __builtin_amdgcn_readfirstlane(row_start[node]);
  const int dg = __builtin_amdgcn_readfirstlane(deg[node]);
  const float t = tvec[layer];
  const int f0 = lane * 4;

  int my_src = 0;
  if (lane < dg) my_src = csr_es[st + lane].y;
  const bf16x4 sv = *(const bf16x4*)&zb[(size_t)node * HD + f0];

  float den[4] = {0.f, 0.f, 0.f, 0.f}, agg[4] = {0.f, 0.f, 0.f, 0.f};
  const int dmain = dg < 64 ? dg : 64;
  int j = 0;
  for (; j + 8 <= dmain; j += 8) {
    bf16x4 zv[8], ev[8];
    #pragma unroll
    for (int u = 0; u < 8; u++) {
      const int sn = __builtin_amdgcn_readlane(my_src, j + u);
      zv[u] = *(const bf16x4*)&zb[(size_t)sn * HD + f0];
      ev[u] = *(const bf16x4*)&ecsr[(size_t)(st + j + u) * HD + f0];
    }
    #pragma unroll
    for (int u = 0; u < 8; u++)
      #pragma unroll
      for (int q = 0; q < 4; q++) {
        const float m  = fmaxf((float)zv[u][q] + (float)ev[u][q], 0.f) + 1e-7f;
        const float ex = __expf(m * t);
        den[q] += ex;
        agg[q] += m * ex;
      }
  }
  for (; j + 4 <= dmain; j += 4) {
    bf16x4 zv[4], ev[4];
    #pragma unroll
    for (int u = 0; u < 4; u++) {
      const int sn = __builtin_amdgcn_readlane(my_src, j + u);
      zv[u] = *(const bf16x4*)&zb[(size_t)sn * HD + f0];
      ev[u] = *(const bf16x4*)&ecsr[(size_t)(st + j + u) * HD + f0];
    }
    #pragma unroll
    for (int u = 0; u < 4; u++)
      #pragma unroll
      for (int q = 0; q < 4; q++) {
        const float m  = fmaxf((float)zv[u][q] + (float)ev[u][q], 0.f) + 1e-7f;
        const float ex = __expf(m * t);
        den[q] += ex;
        agg[q] += m * ex;
      }
  }
  for (; j < dmain; j++) {
    const int sn = __builtin_amdgcn_readlane(my_src, j);
    const bf16x4 zv = *(const bf16x4*)&zb[(size_t)sn * HD + f0];
    const bf16x4 ev = *(const bf16x4*)&ecsr[(size_t)(st + j) * HD + f0];
    #pragma unroll
    for (int q = 0; q < 4; q++) {
      const float m  = fmaxf((float)zv[q] + (float)ev[q], 0.f) + 1e-7f;
      const float ex = __expf(m * t);
      den[q] += ex;
      agg[q] += m * ex;
    }
  }
  for (int jj = 64; jj < dg; jj++) {  // cold path
    const int2 pr = csr_es[st + jj];
    const bf16x4 zv = *(const bf16x4*)&zb[(size_t)pr.y * HD + f0];
    const bf16x4 ev = *(const bf16x4*)&ecsr[(size_t)(st + jj) * HD + f0];
    #pragma unroll
    for (int q = 0; q < 4; q++) {
      const float m  = fmaxf((float)zv[q] + (float)ev[q], 0.f) + 1e-7f;
      const float ex = __expf(m * t);
      den[q] += ex;
      agg[q] += m * ex;
    }
  }
  bf16x4 r;
  #pragma unroll
  for (int q = 0; q < 4; q++) {
    const float res = (dg > 0) ? agg[q] / (den[q] + 1e-16f) : 0.f;
    r[q] = (__bf16)(res + (float)sv[q]);
  }
  *(bf16x4*)&a1[(size_t)node * HD + f0] = r;
}

// ---------------- LN: zb = bf16(relu(LN_256(h))) ----------------
__global__ __launch_bounds__(256)
void k_prenorm(const float* __restrict__ h, const float* __restrict__ g,
               const float* __restrict__ b, __bf16* __restrict__ zb) {
  const int row  = blockIdx.x * 4 + (threadIdx.x >> 6);
  const int lane = threadIdx.x & 63;
  const float4 v = *(const float4*)&h[(size_t)row * HD + lane * 4];
  float s = v.x + v.y + v.z + v.w;
  for (int o = 1; o < 64; o <<= 1) s += __shfl_xor(s, o);
  const float mu = s * (1.f / HD);
  const float dx = v.x - mu, dy = v.y - mu, dz = v.z - mu, dw = v.w - mu;
  float q = dx * dx + dy * dy + dz * dz + dw * dw;
  for (int o = 1; o < 64; o <<= 1) q += __shfl_xor(q, o);
  const float inv = rsqrtf(q * (1.f / HD) + 1e-5f);
  const float4 gv = *(const float4*)&g[lane * 4];
  const float4 bv = *(const float4*)&b[lane * 4];
  bf16x4 r;
  r[0] = (__bf16)fmaxf(dx * inv * gv.x + bv.x, 0.f);
  r[1] = (__bf16)fmaxf(dy * inv * gv.y + bv.y, 0.f);
  r[2] = (__bf16)fmaxf(dz * inv * gv.z + bv.z, 0.f);
  r[3] = (__bf16)fmaxf(dw * inv * gv.w + bv.w, 0.f);
  *(bf16x4*)&zb[(size_t)row * HD + lane * 4] = r;
}

// ---------------- fused final LN + head ----------------
__global__ __launch_bounds__(256)
void k_headln(const float* __restrict__ h, const float* __restrict__ g,
              const float* __restrict__ b, const float* __restrict__ lw,
              const float* __restrict__ lb, float* __restrict__ out) {
  __shared__ float slw[256 * 16];   // [k][c]
  __shared__ float srow[16 * 256];
  const int t = threadIdx.x;
  const size_t row0 = (size_t)blockIdx.x * 16;
  #pragma unroll
  for (int j = 0; j < 16; j++) slw[j * 256 + t] = lw[j * 256 + t];
  const int rl = t >> 4, col = t & 15;
  float v[16];
  float s = 0.f, sq = 0.f;
  #pragma unroll
  for (int j = 0; j < 16; j += 4) {
    const float4 hv = *(const float4*)&h[(row0 + rl) * HD + col * 16 + j];
    v[j] = hv.x; v[j + 1] = hv.y; v[j + 2] = hv.z; v[j + 3] = hv.w;
  }
  #pragma unroll
  for (int j = 0; j < 16; j++) { s += v[j]; sq += v[j] * v[j]; }
  #pragma unroll
  for (int o = 1; o < 16; o <<= 1) { s += __shfl_xor(s, o); sq += __shfl_xor(sq, o); }
  const float mu = s * (1.f / HD);
  const float inv = rsqrtf(sq * (1.f / HD) - mu * mu + 1e-5f);
  #pragma unroll
  for (int j = 0; j < 16; j += 4) {
    const float4 gv = *(const float4*)&g[col * 16 + j];
    const float4 bv = *(const float4*)&b[col * 16 + j];
    srow[rl * 256 + col * 16 + j]     = fmaxf((v[j]     - mu) * inv * gv.x + bv.x, 0.f);
    srow[rl * 256 + col * 16 + j + 1] = fmaxf((v[j + 1] - mu) * inv * gv.y + bv.y, 0.f);
    srow[rl * 256 + col * 16 + j + 2] = fmaxf((v[j + 2] - mu) * inv * gv.z + bv.z, 0.f);
    srow[rl * 256 + col * 16 + j + 3] = fmaxf((v[j + 3] - mu) * inv * gv.w + bv.w, 0.f);
  }
  __syncthreads();
  float acc = lb[col];
  #pragma unroll 8
  for (int k = 0; k < 256; k++) acc += srow[rl * 256 + k] * slw[k * 16 + col];
  out[(row0 + rl) * 16 + col] = acc;
}

// ---------------- host launch ----------------
extern "C" void kernel_launch(void* const* d_in, const int* in_sizes, int n_in,
                              void* d_out, int out_size, void* d_ws, size_t ws_size,
                              hipStream_t stream) {
  const float* x     = (const float*)d_in[0];
  const int*   ei    = (const int*)d_in[1];
  const float* ea    = (const float*)d_in[2];
  const float* enc_w = (const float*)d_in[3];
  const float* enc_b = (const float*)d_in[4];
  const float* ee_w  = (const float*)d_in[5];
  const float* ee_b  = (const float*)d_in[6];
  const float* w1    = (const float*)d_in[7];
  const float* b1    = (const float*)d_in[8];
  const float* lng   = (const float*)d_in[9];
  const float* lnb   = (const float*)d_in[10];
  const float* w2    = (const float*)d_in[11];
  const float* b2    = (const float*)d_in[12];
  const float* tvec  = (const float*)d_in[13];
  const float* ng    = (const float*)d_in[14];
  const float* nb    = (const float*)d_in[15];
  const float* lin_w = (const float*)d_in[16];
  const float* lin_b = (const float*)d_in[17];

  uint8_t* p = (uint8_t*)d_ws;
  auto alloc = [&](size_t bytes) { uint8_t* r = p; p += (bytes + 255) & ~(size_t)255; return r; };
  __bf16* e_csr  = (__bf16*)alloc((size_t)NE * HD * 2);
  float*  h      = (float*) alloc((size_t)NN * HD * 4);
  __bf16* hb     = (__bf16*)alloc((size_t)NN * HD * 2);
  __bf16* zb     = (__bf16*)alloc((size_t)NN * HD * 2);
  __bf16* a1     = (__bf16*)alloc((size_t)NN * HD * 2);
  __bf16* c1b    = (__bf16*)alloc((size_t)NN * HD2 * 2);
  float2* pstats = (float2*)alloc((size_t)NN * 4 * 8);
  __bf16* xbf    = (__bf16*)alloc((size_t)NN * DIN * 2);
  __bf16* eabf   = (__bf16*)alloc((size_t)NE * DE * 2);
  __bf16* enc_wT = (__bf16*)alloc((size_t)HD * DIN * 2);
  __bf16* ee_wT  = (__bf16*)alloc((size_t)HD * DE * 2);
  __bf16* w1T    = (__bf16*)alloc((size_t)4 * HD2 * HD * 2);
  __bf16* w2T    = (__bf16*)alloc((size_t)4 * HD * HD2 * 2);
  int* deg       = (int*)alloc((size_t)NN * 4);
  int* cursor    = (int*)alloc((size_t)NN * 4);   // contiguous with deg -> one memset
  int* row_start = (int*)alloc((size_t)NN * 4);
  int* posmap    = (int*)alloc((size_t)NE * 4);
  int2* csr_es   = (int2*)alloc((size_t)NE * 8);

  const int* srcp = ei;
  const int* dstp = ei + NE;

  hipMemsetAsync(deg, 0, (size_t)NN * 8, stream);  // deg + cursor

  const int prep_total = DIN * HD + DE * HD + 4 * HD * HD2 + 4 * HD2 * HD +
                         NN * DIN / 4 + NE * DE / 4 + NE;   // + histogram range
  k_prep<<<(prep_total + 255) / 256, 256, 0, stream>>>(enc_w, ee_w, w1, w2, x, ea,
                                                       dstp, deg,
                                                       enc_wT, ee_wT, w1T, w2T, xbf, eabf);
  k_scan<<<1, 1024, 0, stream>>>(deg, row_start);
  k_scatter<<<NE / 256, 256, 0, stream>>>(srcp, dstp, row_start, cursor, csr_es);
  k_sortw<<<NN / 4, 256, 0, stream>>>(row_start, deg, csr_es, posmap);

  // node encoder: h(f32) + hb(bf16)
  k_gemm<0, 2, 0, 0><<<(NN / 128) * (HD / 128), 256, 0, stream>>>(
      xbf, enc_wT, enc_b, nullptr, h, hb, nullptr, nullptr, NN, HD, DIN);
  // edge encoder -> e_csr (CSR-position-ordered rows)
  k_gemm<0, 1, 0, 1><<<(NE / 128) * (HD / 128), 256, 0, stream>>>(
      eabf, ee_wT, ee_b, nullptr, nullptr, e_csr, posmap, nullptr, NE, HD, DE);

  for (int i = 0; i < 4; i++) {
    const __bf16* zin = (i == 0) ? hb : zb;
    k_msg<<<NN / 4, 256, 0, stream>>>(zin, e_csr, row_start, deg, csr_es, tvec, i, a1);
    // GEMM1: c1b = bf16(a1 @ w1 + b1) + per-row stats
    k_gemm<0, 1, 1, 0><<<(NN / 128) * (HD2 / 128), 256, 0, stream>>>(
        a1, w1T + (size_t)i * HD2 * HD, b1 + (size_t)i * HD2, nullptr, nullptr, c1b,
        nullptr, pstats, NN, HD2, HD);
    // GEMM2 (fused LN512+ReLU on A): h = relu(LN(c1)) @ w2 + b2 (+h)
    if (i == 0)
      k_gemm2<0><<<(NN / 128) * (HD / 128), 256, 0, stream>>>(
          c1b, w2T + (size_t)i * HD * HD2, b2 + (size_t)i * HD, nullptr, pstats,
          lng + (size_t)i * HD2, lnb + (size_t)i * HD2, h, HD);
    else
      k_gemm2<1><<<(NN / 128) * (HD / 128), 256, 0, stream>>>(
          c1b, w2T + (size_t)i * HD * HD2, b2 + (size_t)i * HD, h, pstats,
          lng + (size_t)i * HD2, lnb + (size_t)i * HD2, h, HD);
    if (i < 3)
      k_prenorm<<<NN / 4, 256, 0, stream>>>(h, ng + (size_t)(i + 1) * HD,
                                            nb + (size_t)(i + 1) * HD, zb);
  }

  k_headln<<<NN / 16, 256, 0, stream>>>(h, ng, nb, lin_w, lin_b, (float*)d_out);
}